// Round 1
// baseline (1415.701 us; speedup 1.0000x reference)
//
#include <hip/hip_runtime.h>

#define N_NODES 50000
#define MPAD    50048   // 391*128
#define DIM     1024
#define HEAD    16
#define KV      128
#define HD      64

typedef unsigned short ushort_t;
typedef short short8 __attribute__((ext_vector_type(8)));
typedef float f32x4 __attribute__((ext_vector_type(4)));

__device__ inline unsigned short f2bf(float f){
  union { float f; unsigned u; } v; v.f = f;
  unsigned u = v.u;
  unsigned r = (u + 0x7FFFu + ((u >> 16) & 1u)) >> 16;
  return (unsigned short)r;
}
__device__ inline float bf2f(unsigned short u){
  union { unsigned u; float f; } v; v.u = ((unsigned)u) << 16; return v.f;
}

__device__ inline void gload_lds16(const void* g, void* l){
  __builtin_amdgcn_global_load_lds(
      (const __attribute__((address_space(1))) void*)g,
      (__attribute__((address_space(3))) void*)l, 16, 0, 0);
}

// fragment loads: row-major [*][64] or [*][128] bf16 LDS tile, 16B-chunk XOR-swizzled by (row&7)
__device__ inline short8 frag64(const ushort_t* lds, int row, int kk, int lane){
  int c  = kk*4 + (lane >> 4);
  int cc = c ^ (row & 7);
  return *(const short8*)(lds + row*64 + cc*8);
}
__device__ inline short8 frag128(const ushort_t* lds, int row, int kk, int lane){
  int c  = kk*4 + (lane >> 4);
  int cc = c ^ (row & 7);
  return *(const short8*)(lds + row*128 + cc*8);
}
// pad-72 (stride 72 shorts = 144B) plain layout
__device__ inline short8 fragp72(const ushort_t* lds, int row, int kk, int lane){
  return *(const short8*)(lds + row*72 + kk*32 + (lane>>4)*8);
}

// ---------------- prep kernels ----------------
__global__ void k_zero(float* p, int n){
  int i = blockIdx.x*256 + threadIdx.x;
  if (i < n) p[i] = 0.f;
}

// W concat (rows 0..1023 = Wq, 1024..2047 = Wv), bf16, 16B-chunk swizzle keyed by row&7
__global__ void k_prep_w(const float* __restrict__ Wq, const float* __restrict__ Wv,
                         ushort_t* __restrict__ w_bf){
  int idx = blockIdx.x*256 + threadIdx.x;   // 2048*1024
  int j = idx >> 10, k = idx & 1023;
  float v = (j < 1024) ? Wq[idx] : Wv[(size_t)(j-1024)*1024 + k];
  int d = k & 63;
  int scol = (k & ~63) | ((((d>>3) ^ (j & 7)) & 7) << 3) | (d & 7);
  w_bf[(size_t)j*1024 + scol] = f2bf(v);
}

// key_bf[h][r][swz(d, r)]  from key_p[r][h][d]
__global__ void k_prep_key(const float* __restrict__ key_p, ushort_t* __restrict__ key_bf){
  int idx = blockIdx.x*256 + threadIdx.x;   // 16*128*64
  int h = idx >> 13, rem = idx & 8191;
  int r = rem >> 6, d = rem & 63;
  float v = key_p[(size_t)(r*HEAD + h)*HD + d];
  int pos = ((((d>>3) ^ (r & 7)) & 7) << 3) | (d & 7);
  key_bf[(size_t)h*8192 + r*64 + pos] = f2bf(v);
}

// ---------------- big GEMM: qxv = x @ [Wq;Wv]^T + [bq;bv] ----------------
// 128x128 tile, BK=64, 4 waves (2x2), 16x16x32 bf16 MFMA.
// q-half (cols<1024) stored chunk-swizzled by row&7 for later global_load_lds staging.
__global__ __launch_bounds__(256) void k_gemm(const float* __restrict__ x,
    const ushort_t* __restrict__ w_bf, const float* __restrict__ bq,
    const float* __restrict__ bv, ushort_t* __restrict__ qxv){
  __shared__ ushort_t a_lds[128*64];
  __shared__ ushort_t b_lds[128*64];
  const int tid = threadIdx.x, lane = tid & 63;
  const int wid = tid >> 6, wr = wid >> 1, wc = wid & 1;
  const int bn0 = blockIdx.x * 128, bm0 = blockIdx.y * 128;

  f32x4 acc[4][4];
  for (int m=0;m<4;m++) for (int n=0;n<4;n++) acc[m][n] = (f32x4){0.f,0.f,0.f,0.f};

  for (int kt = 0; kt < 16; ++kt){
    const int k0 = kt * 64;
    // A: reg-staged fp32 -> bf16, swizzled ds_write
    #pragma unroll
    for (int it = 0; it < 4; ++it){
      int chunk = it*256 + tid;
      int r = chunk >> 3, c = chunk & 7;
      int grow = bm0 + r;
      float f[8];
      if (grow < N_NODES){
        const float4* s = (const float4*)(x + (size_t)grow*DIM + k0 + c*8);
        float4 f0 = s[0], f1 = s[1];
        f[0]=f0.x; f[1]=f0.y; f[2]=f0.z; f[3]=f0.w;
        f[4]=f1.x; f[5]=f1.y; f[6]=f1.z; f[7]=f1.w;
      } else {
        #pragma unroll
        for (int i=0;i<8;i++) f[i]=0.f;
      }
      short8 v;
      #pragma unroll
      for (int i=0;i<8;i++) v[i] = (short)f2bf(f[i]);
      *(short8*)(a_lds + r*64 + ((c ^ (r&7)) & 7)*8) = v;
    }
    // B: direct global->LDS (w_bf already swizzled)
    #pragma unroll
    for (int it = 0; it < 4; ++it){
      int chunk = it*256 + tid;
      int r = chunk >> 3, c = chunk & 7;
      gload_lds16(w_bf + (size_t)(bn0 + r)*1024 + k0 + c*8, b_lds + it*2048 + tid*8);
    }
    __syncthreads();
    #pragma unroll
    for (int kk = 0; kk < 2; ++kk){
      short8 af[4], bfr[4];
      #pragma unroll
      for (int m=0;m<4;m++) af[m]  = frag64(a_lds, wr*64 + m*16 + (lane&15), kk, lane);
      #pragma unroll
      for (int n=0;n<4;n++) bfr[n] = frag64(b_lds, wc*64 + n*16 + (lane&15), kk, lane);
      #pragma unroll
      for (int m=0;m<4;m++)
        #pragma unroll
        for (int n=0;n<4;n++)
          acc[m][n] = __builtin_amdgcn_mfma_f32_16x16x32_bf16(af[m], bfr[n], acc[m][n], 0,0,0);
    }
    __syncthreads();
  }
  // epilogue: bias, bf16, store (q-half swizzled)
  #pragma unroll
  for (int n=0;n<4;n++){
    int col = bn0 + wc*64 + n*16 + (lane & 15);
    float bias = (col < 1024) ? bq[col] : bv[col - 1024];
    #pragma unroll
    for (int m=0;m<4;m++){
      #pragma unroll
      for (int j=0;j<4;j++){
        int row = bm0 + wr*64 + m*16 + (lane>>4)*4 + j;
        float val = acc[m][n][j] + bias;
        int scol = col;
        if (col < 1024){
          int d = col & 63;
          scol = (col & ~63) | ((((d>>3) ^ (row & 7)) & 7) << 3) | (d & 7);
        }
        qxv[(size_t)row*2048 + scol] = f2bf(val);
      }
    }
  }
}

// ---------------- attn passes ----------------
// PHASE 0: colsumA = sum_n Q0 ; v_ws += sigmoid(attn)^T @ xv   (per head)
// PHASE 1: w=1/(128*cs_in); u=1/(50000*sum_r Q0*w); cs_out += sum_n u*Q0
// PHASE 2: w3,u3 -> cons = 50000*u3*Q0*w3 ; out = sig(a)*xv + sig(b)*(cons@v)
template<int PHASE>
__global__ __launch_bounds__(256) void k_attn(
    const ushort_t* __restrict__ qxv, const ushort_t* __restrict__ key_bf,
    const float* __restrict__ node_index, const float* __restrict__ Wb,
    const float* __restrict__ bb, const float* __restrict__ colsum_in,
    float* __restrict__ colsum_out, float* __restrict__ v_ws,
    const float* __restrict__ alpha, const float* __restrict__ beta,
    float* __restrict__ out)
{
  extern __shared__ char smem[];
  ushort_t* q_lds   = (ushort_t*)(smem);          // 64x64 bf16 (8KB)
  ushort_t* key_lds = (ushort_t*)(smem + 8192);   // 128x64 bf16 (16KB)
  float* ni_lds  = (float*)(smem + 24576);        // 64x4
  float* wb_lds  = (float*)(smem + 25600);        // 128x5
  float* red_lds = (float*)(smem + 28160);        // 2 x [4][64]
  float* col_acc = (float*)(smem + 30208);        // 128
  float* w_lds   = (float*)(smem + 30720);        // 128
  ushort_t* sigT     = (ushort_t*)(smem + 31232); // PHASE0: 128x72 bf16
  ushort_t* xvT      = (ushort_t*)(smem + 31232 + 18432); // PHASE0: 64x72 bf16
  ushort_t* cons_lds = (ushort_t*)(smem + 31232); // PHASE2: 64x128 bf16 (swz)
  ushort_t* vT       = (ushort_t*)(smem + 31232 + 16384); // PHASE2: 64x128 bf16 (swz)
  float* out_lds = (float*)(smem);                // PHASE2: 64x68 f32 (over q/key)

  const int tid = threadIdx.x, lane = tid & 63, wid = tid >> 6;
  const int h  = blockIdx.x & 15;
  const int i0 = (blockIdx.x >> 4) * 64;

  // ---- stage ----
  #pragma unroll
  for (int it = 0; it < 2; ++it){
    int chunk = it*256 + tid;
    int r = chunk >> 3, c = chunk & 7;
    gload_lds16(qxv + (size_t)(i0 + r)*2048 + h*64 + c*8, q_lds + it*2048 + tid*8);
  }
  #pragma unroll
  for (int it = 0; it < 4; ++it){
    int chunk = it*256 + tid;
    int r = chunk >> 3, c = chunk & 7;
    gload_lds16(key_bf + (size_t)h*8192 + r*64 + c*8, key_lds + it*2048 + tid*8);
  }
  { int r = tid >> 2, c = tid & 3;
    ni_lds[tid] = (i0 + r < N_NODES) ? node_index[(size_t)(i0 + r)*4 + c] : 0.f; }
  if (tid < 128){
    #pragma unroll
    for (int c=0;c<4;c++) wb_lds[tid*5+c] = Wb[(size_t)(h*128 + tid)*4 + c];
    wb_lds[tid*5+4] = bb[h*128 + tid];
    if (PHASE >= 1) w_lds[tid] = 1.f / (128.f * colsum_in[h*128 + tid]);
  }
  __syncthreads();

  // ---- attn^T = key @ q^T / 8 + bias^T ; element (r, nn) ----
  f32x4 acc[2][4];
  for (int m=0;m<2;m++) for (int n=0;n<4;n++) acc[m][n] = (f32x4){0.f,0.f,0.f,0.f};
  #pragma unroll
  for (int kk = 0; kk < 2; ++kk){
    short8 kf[2];
    #pragma unroll
    for (int m=0;m<2;m++) kf[m] = frag64(key_lds, wid*32 + m*16 + (lane&15), kk, lane);
    #pragma unroll
    for (int n=0;n<4;n++){
      short8 qf = frag64(q_lds, n*16 + (lane&15), kk, lane);
      #pragma unroll
      for (int m=0;m<2;m++)
        acc[m][n] = __builtin_amdgcn_mfma_f32_16x16x32_bf16(kf[m], qf, acc[m][n], 0,0,0);
    }
  }

  float nif[4][4];
  #pragma unroll
  for (int n=0;n<4;n++){
    int nn = n*16 + (lane&15);
    #pragma unroll
    for (int c=0;c<4;c++) nif[n][c] = ni_lds[nn*4+c];
  }
  float a[2][4][4];
  #pragma unroll
  for (int m=0;m<2;m++){
    #pragma unroll
    for (int j=0;j<4;j++){
      int r = wid*32 + m*16 + (lane>>4)*4 + j;
      float w0 = wb_lds[r*5+0], w1 = wb_lds[r*5+1];
      float w2 = wb_lds[r*5+2], w3 = wb_lds[r*5+3], w4 = wb_lds[r*5+4];
      #pragma unroll
      for (int n=0;n<4;n++){
        float b = w4 + w0*nif[n][0] + w1*nif[n][1] + w2*nif[n][2] + w3*nif[n][3];
        a[m][n][j] = acc[m][n][j]*0.125f + b;
      }
    }
  }

  float vmask[4];
  #pragma unroll
  for (int n=0;n<4;n++) vmask[n] = (i0 + n*16 + (lane&15) < N_NODES) ? 1.f : 0.f;

  if constexpr (PHASE == 0){
    // sigmoid -> sigT (A operand, [r][nn] pad-72), masked
    #pragma unroll
    for (int m=0;m<2;m++) for (int n=0;n<4;n++) for (int j=0;j<4;j++){
      int r  = wid*32 + m*16 + (lane>>4)*4 + j;
      int nn = n*16 + (lane&15);
      float sg = vmask[n] / (1.f + __expf(-a[m][n][j]));
      sigT[r*72 + nn] = f2bf(sg);
    }
    // xv^T -> xvT ([d][nn] pad-72)
    { int d = tid & 63, q4 = tid >> 6;
      #pragma unroll
      for (int i=0;i<16;i++){
        int nn = q4*16 + i;
        xvT[d*72 + nn] = qxv[(size_t)(i0+nn)*2048 + 1024 + h*64 + d];
      }
    }
  }
  if constexpr (PHASE == 2){
    // v^T -> vT ([d][r=128] chunk-swizzled by d&7)
    int r = tid >> 1, dh = (tid & 1)*32;
    #pragma unroll
    for (int i=0;i<32;i++){
      int d = dh + i;
      float v = v_ws[((size_t)r*16 + h)*64 + d];
      vT[d*128 + ((r>>3) ^ (d&7))*8 + (r&7)] = f2bf(v);
    }
  }

  // ---- softmax over r (columns of attn^T) ----
  float pm[4];
  #pragma unroll
  for (int n=0;n<4;n++){
    float m0 = a[0][n][0];
    #pragma unroll
    for (int m=0;m<2;m++) for (int j=0;j<4;j++) m0 = fmaxf(m0, a[m][n][j]);
    m0 = fmaxf(m0, __shfl_xor(m0, 16));
    m0 = fmaxf(m0, __shfl_xor(m0, 32));
    pm[n] = m0;
  }
  if (lane < 16){
    #pragma unroll
    for (int n=0;n<4;n++) red_lds[wid*64 + n*16 + lane] = pm[n];
  }
  __syncthreads();   // also covers sigT/xvT/vT writes

  float mnn[4], snn[4];
  #pragma unroll
  for (int n=0;n<4;n++){
    int nn = n*16 + (lane&15);
    float m0 = red_lds[nn];
    m0 = fmaxf(m0, red_lds[64+nn]); m0 = fmaxf(m0, red_lds[128+nn]); m0 = fmaxf(m0, red_lds[192+nn]);
    mnn[n] = m0;
  }
  #pragma unroll
  for (int n=0;n<4;n++){
    float s = 0.f;
    #pragma unroll
    for (int m=0;m<2;m++) for (int j=0;j<4;j++){
      float e = __expf(a[m][n][j] - mnn[n]);
      a[m][n][j] = e; s += e;
    }
    s += __shfl_xor(s, 16); s += __shfl_xor(s, 32);
    snn[n] = s;
  }
  if (lane < 16){
    #pragma unroll
    for (int n=0;n<4;n++) red_lds[256 + wid*64 + n*16 + lane] = snn[n];
  }

  if constexpr (PHASE == 0){
    // v-acc MFMA: D[r][d] = sum_nn sigT[r][nn] * xvT[d][nn]
    f32x4 vac[2][4];
    for (int m=0;m<2;m++) for (int n=0;n<4;n++) vac[m][n] = (f32x4){0.f,0.f,0.f,0.f};
    #pragma unroll
    for (int kk=0;kk<2;kk++){
      short8 sa[2];
      #pragma unroll
      for (int m=0;m<2;m++) sa[m] = fragp72(sigT, wid*32 + m*16 + (lane&15), kk, lane);
      #pragma unroll
      for (int n=0;n<4;n++){
        short8 xf = fragp72(xvT, n*16 + (lane&15), kk, lane);
        #pragma unroll
        for (int m=0;m<2;m++)
          vac[m][n] = __builtin_amdgcn_mfma_f32_16x16x32_bf16(sa[m], xf, vac[m][n], 0,0,0);
      }
    }
    #pragma unroll
    for (int m=0;m<2;m++) for (int n=0;n<4;n++) for (int j=0;j<4;j++){
      int r = wid*32 + m*16 + (lane>>4)*4 + j;
      int d = n*16 + (lane&15);
      atomicAdd(&v_ws[((size_t)r*16 + h)*64 + d], vac[m][n][j]);
    }
  }
  __syncthreads();

  #pragma unroll
  for (int n=0;n<4;n++){
    int nn = n*16 + (lane&15);
    snn[n] = red_lds[256+nn] + red_lds[256+64+nn] + red_lds[256+128+nn] + red_lds[256+192+nn];
  }
  // Q0 = exp(20 * softmax)
  #pragma unroll
  for (int n=0;n<4;n++){
    float inv = 20.f / snn[n];
    #pragma unroll
    for (int m=0;m<2;m++) for (int j=0;j<4;j++)
      a[m][n][j] = __expf(a[m][n][j] * inv);
  }

  float uval[4];
  if constexpr (PHASE >= 1){
    #pragma unroll
    for (int n=0;n<4;n++){
      float s = 0.f;
      #pragma unroll
      for (int m=0;m<2;m++){
        #pragma unroll
        for (int j=0;j<4;j++){
          int r = wid*32 + m*16 + (lane>>4)*4 + j;
          s += a[m][n][j] * w_lds[r];
        }
      }
      s += __shfl_xor(s, 16); s += __shfl_xor(s, 32);
      uval[n] = s;
    }
    if (lane < 16){
      #pragma unroll
      for (int n=0;n<4;n++) red_lds[wid*64 + n*16 + lane] = uval[n];
    }
    __syncthreads();
    #pragma unroll
    for (int n=0;n<4;n++){
      int nn = n*16 + (lane&15);
      float s = red_lds[nn] + red_lds[64+nn] + red_lds[128+nn] + red_lds[192+nn];
      uval[n] = 1.f / (50000.f * s);
    }
  }

  if constexpr (PHASE <= 1){
    float cs[2][4];
    #pragma unroll
    for (int m=0;m<2;m++){
      #pragma unroll
      for (int j=0;j<4;j++){
        float s = 0.f;
        #pragma unroll
        for (int n=0;n<4;n++){
          float t = a[m][n][j] * vmask[n];
          if (PHASE == 1) t *= uval[n];
          s += t;
        }
        s += __shfl_xor(s, 1); s += __shfl_xor(s, 2);
        s += __shfl_xor(s, 4); s += __shfl_xor(s, 8);
        cs[m][j] = s;
      }
    }
    if ((lane & 15) == 0){
      #pragma unroll
      for (int m=0;m<2;m++) for (int j=0;j<4;j++){
        int r = wid*32 + m*16 + (lane>>4)*4 + j;
        col_acc[r] = cs[m][j];
      }
    }
    __syncthreads();
    if (tid < 128) atomicAdd(&colsum_out[h*128 + tid], col_acc[tid]);
  }

  if constexpr (PHASE == 2){
    // cons[nn][r] = 50000 * u3[nn] * Q0 * w3[r]  (chunk-swizzled by nn&7)
    #pragma unroll
    for (int m=0;m<2;m++) for (int n=0;n<4;n++) for (int j=0;j<4;j++){
      int r  = wid*32 + m*16 + (lane>>4)*4 + j;
      int nn = n*16 + (lane&15);
      float cv = 50000.f * uval[n] * a[m][n][j] * w_lds[r];
      cons_lds[nn*128 + ((r>>3) ^ (nn&7))*8 + (r&7)] = f2bf(cv);
    }
    __syncthreads();
    // v_final^T[d][nn] = sum_r vT[d][r] * cons[nn][r]
    f32x4 oac[4];
    for (int n=0;n<4;n++) oac[n] = (f32x4){0.f,0.f,0.f,0.f};
    #pragma unroll
    for (int kk=0;kk<4;kk++){
      short8 va = frag128(vT, wid*16 + (lane&15), kk, lane);
      #pragma unroll
      for (int n=0;n<4;n++){
        short8 cf = frag128(cons_lds, n*16 + (lane&15), kk, lane);
        oac[n] = __builtin_amdgcn_mfma_f32_16x16x32_bf16(va, cf, oac[n], 0,0,0);
      }
    }
    #pragma unroll
    for (int n=0;n<4;n++) for (int j=0;j<4;j++){
      int d  = wid*16 + (lane>>4)*4 + j;
      int nn = n*16 + (lane&15);
      out_lds[nn*68 + d] = oac[n][j];
    }
    __syncthreads();
    float sa = 1.f/(1.f + __expf(-alpha[h]));
    float sb = 1.f/(1.f + __expf(-beta[h]));
    int nn = tid >> 2, d0 = (tid & 3)*16;
    if (i0 + nn < N_NODES){
      #pragma unroll
      for (int g=0; g<4; ++g){
        float4 vf = *(const float4*)(out_lds + nn*68 + d0 + g*4);
        const ushort_t* xp = qxv + (size_t)(i0+nn)*2048 + 1024 + h*64 + d0 + g*4;
        float4 o;
        o.x = sa*bf2f(xp[0]) + sb*vf.x;
        o.y = sa*bf2f(xp[1]) + sb*vf.y;
        o.z = sa*bf2f(xp[2]) + sb*vf.z;
        o.w = sa*bf2f(xp[3]) + sb*vf.w;
        *(float4*)(out + (size_t)(i0+nn)*1024 + h*64 + d0 + g*4) = o;
      }
    }
  }
}

extern "C" void kernel_launch(void* const* d_in, const int* in_sizes, int n_in,
                              void* d_out, int out_size, void* d_ws, size_t ws_size,
                              hipStream_t stream){
  const float* x     = (const float*)d_in[0];
  const float* ni    = (const float*)d_in[1];
  const float* Wq    = (const float*)d_in[2];
  const float* bq    = (const float*)d_in[3];
  const float* keyp  = (const float*)d_in[4];
  const float* Wv    = (const float*)d_in[5];
  const float* bv    = (const float*)d_in[6];
  const float* alpha = (const float*)d_in[7];
  const float* beta  = (const float*)d_in[8];
  const float* Wb    = (const float*)d_in[9];
  const float* bb    = (const float*)d_in[10];
  float* out = (float*)d_out;

  char* ws = (char*)d_ws;
  ushort_t* qxv    = (ushort_t*)ws;                       // MPAD*2048 bf16
  ushort_t* w_bf   = (ushort_t*)(ws + 205000704);         // 2048*1024 bf16
  ushort_t* key_bf = (ushort_t*)(ws + 209195008);         // 16*128*64 bf16
  float*    v_ws   = (float*)(ws + 209457152);            // 128*16*64 f32
  float*    cs     = (float*)(ws + 209981440);            // 3*2048 f32

  k_zero<<<dim3((131072 + 6144 + 255)/256), 256, 0, stream>>>(v_ws, 131072 + 6144);
  k_prep_w<<<dim3(2048*1024/256), 256, 0, stream>>>(Wq, Wv, w_bf);
  k_prep_key<<<dim3(HEAD*KV*HD/256), 256, 0, stream>>>(keyp, key_bf);
  k_gemm<<<dim3(16, 391), 256, 0, stream>>>(x, w_bf, bq, bv, qxv);

  dim3 ag(782*16);
  k_attn<0><<<ag, 256, 58880, stream>>>(qxv, key_bf, ni, Wb, bb, nullptr,  cs,       v_ws, alpha, beta, out);
  k_attn<1><<<ag, 256, 31232, stream>>>(qxv, key_bf, ni, Wb, bb, cs,       cs+2048,  v_ws, alpha, beta, out);
  k_attn<1><<<ag, 256, 31232, stream>>>(qxv, key_bf, ni, Wb, bb, cs+2048,  cs+4096,  v_ws, alpha, beta, out);
  k_attn<2><<<ag, 256, 64000, stream>>>(qxv, key_bf, ni, Wb, bb, cs+4096,  nullptr,  v_ws, alpha, beta, out);
}

// Round 2
// 1269.330 us; speedup vs baseline: 1.1153x; 1.1153x over previous
//
#include <hip/hip_runtime.h>

#define N_NODES 50000
#define MPAD    50048   // 391*128
#define DIM     1024
#define HEAD    16
#define KV      128
#define HD      64

typedef unsigned short ushort_t;
typedef short short8 __attribute__((ext_vector_type(8)));
typedef float f32x4 __attribute__((ext_vector_type(4)));

__device__ inline unsigned short f2bf(float f){
  union { float f; unsigned u; } v; v.f = f;
  unsigned u = v.u;
  unsigned r = (u + 0x7FFFu + ((u >> 16) & 1u)) >> 16;
  return (unsigned short)r;
}
__device__ inline float bf2f(unsigned short u){
  union { unsigned u; float f; } v; v.u = ((unsigned)u) << 16; return v.f;
}

__device__ inline void gload_lds16(const void* g, void* l){
  __builtin_amdgcn_global_load_lds(
      (const __attribute__((address_space(1))) void*)g,
      (__attribute__((address_space(3))) void*)l, 16, 0, 0);
}

// fragment loads: row-major [*][64] or [*][128] bf16 LDS tile, 16B-chunk XOR-swizzled by (row&7)
__device__ inline short8 frag64(const ushort_t* lds, int row, int kk, int lane){
  int c  = kk*4 + (lane >> 4);
  int cc = c ^ (row & 7);
  return *(const short8*)(lds + row*64 + cc*8);
}
__device__ inline short8 frag128(const ushort_t* lds, int row, int kk, int lane){
  int c  = kk*4 + (lane >> 4);
  int cc = c ^ (row & 7);
  return *(const short8*)(lds + row*128 + cc*8);
}
// pad-72 (stride 72 shorts = 144B) plain layout
__device__ inline short8 fragp72(const ushort_t* lds, int row, int kk, int lane){
  return *(const short8*)(lds + row*72 + kk*32 + (lane>>4)*8);
}

// ---------------- prep kernels ----------------
__global__ void k_zero(float* p, int n){
  int i = blockIdx.x*256 + threadIdx.x;
  if (i < n) p[i] = 0.f;
}

// x fp32 -> bf16, 16B-chunk swizzle keyed by row&7 (for global_load_lds staging)
__global__ void k_prep_x(const float* __restrict__ x, ushort_t* __restrict__ x_bf){
  int idx = blockIdx.x*256 + threadIdx.x;   // N_NODES*128 chunks of 8
  int row = idx >> 7, c = idx & 127;
  const float4* s = (const float4*)(x + (size_t)row*1024 + c*8);
  float4 f0 = s[0], f1 = s[1];
  short8 v;
  v[0]=(short)f2bf(f0.x); v[1]=(short)f2bf(f0.y); v[2]=(short)f2bf(f0.z); v[3]=(short)f2bf(f0.w);
  v[4]=(short)f2bf(f1.x); v[5]=(short)f2bf(f1.y); v[6]=(short)f2bf(f1.z); v[7]=(short)f2bf(f1.w);
  int sc = (c & ~7) | ((c ^ row) & 7);
  *(short8*)(x_bf + (size_t)row*1024 + sc*8) = v;
}

// W concat (rows 0..1023 = Wq, 1024..2047 = Wv), bf16, 16B-chunk swizzle keyed by row&7
__global__ void k_prep_w(const float* __restrict__ Wq, const float* __restrict__ Wv,
                         ushort_t* __restrict__ w_bf){
  int idx = blockIdx.x*256 + threadIdx.x;   // 2048*1024
  int j = idx >> 10, k = idx & 1023;
  float v = (j < 1024) ? Wq[idx] : Wv[(size_t)(j-1024)*1024 + k];
  int d = k & 63;
  int scol = (k & ~63) | ((((d>>3) ^ (j & 7)) & 7) << 3) | (d & 7);
  w_bf[(size_t)j*1024 + scol] = f2bf(v);
}

// key_bf[h][r][swz(d, r)]  from key_p[r][h][d]
__global__ void k_prep_key(const float* __restrict__ key_p, ushort_t* __restrict__ key_bf){
  int idx = blockIdx.x*256 + threadIdx.x;   // 16*128*64
  int h = idx >> 13, rem = idx & 8191;
  int r = rem >> 6, d = rem & 63;
  float v = key_p[(size_t)(r*HEAD + h)*HD + d];
  int pos = ((((d>>3) ^ (r & 7)) & 7) << 3) | (d & 7);
  key_bf[(size_t)h*8192 + r*64 + pos] = f2bf(v);
}

// sum the 8 v-slices
__global__ void k_vreduce(const float* __restrict__ vsl, float* __restrict__ vout){
  int i = blockIdx.x*256 + threadIdx.x;   // 131072
  float s = 0.f;
  #pragma unroll
  for (int k=0;k<8;k++) s += vsl[k*131072 + i];
  vout[i] = s;
}

// ---------------- big GEMM: [q|xv] = x @ [Wq;Wv]^T + [bq;bv] ----------------
// 128x128 tile, BK=64, 4 waves (2x2), 16x16x32 bf16 MFMA, both operands via global_load_lds.
// q-half -> q_bf (bf16, chunk-swizzled by row&7); xv-half -> xv_out f32 (= d_out scratch).
__global__ __launch_bounds__(256) void k_gemm(const ushort_t* __restrict__ x_bf,
    const ushort_t* __restrict__ w_bf, const float* __restrict__ bq,
    const float* __restrict__ bv, ushort_t* __restrict__ q_bf, float* xv_out){
  __shared__ ushort_t a_lds[128*64];
  __shared__ ushort_t b_lds[128*64];
  const int tid = threadIdx.x, lane = tid & 63;
  const int wid = tid >> 6, wr = wid >> 1, wc = wid & 1;
  // bijective XCD swizzle: 6256 = 8 * 782; same-row-panel column tiles land on one XCD
  int b = blockIdx.x;
  int wg = (b & 7)*782 + (b >> 3);
  const int bm0 = (wg >> 4) * 128, bn0 = (wg & 15) * 128;

  f32x4 acc[4][4];
  for (int m=0;m<4;m++) for (int n=0;n<4;n++) acc[m][n] = (f32x4){0.f,0.f,0.f,0.f};

  for (int kt = 0; kt < 16; ++kt){
    const int k0 = kt * 64;
    #pragma unroll
    for (int it = 0; it < 4; ++it){
      int chunk = it*256 + tid;
      int r = chunk >> 3, c = chunk & 7;
      gload_lds16(x_bf + (size_t)(bm0 + r)*1024 + k0 + c*8, a_lds + chunk*8);
    }
    #pragma unroll
    for (int it = 0; it < 4; ++it){
      int chunk = it*256 + tid;
      int r = chunk >> 3, c = chunk & 7;
      gload_lds16(w_bf + (size_t)(bn0 + r)*1024 + k0 + c*8, b_lds + chunk*8);
    }
    __syncthreads();
    #pragma unroll
    for (int kk = 0; kk < 2; ++kk){
      short8 af[4], bfr[4];
      #pragma unroll
      for (int m=0;m<4;m++) af[m]  = frag64(a_lds, wr*64 + m*16 + (lane&15), kk, lane);
      #pragma unroll
      for (int n=0;n<4;n++) bfr[n] = frag64(b_lds, wc*64 + n*16 + (lane&15), kk, lane);
      #pragma unroll
      for (int m=0;m<4;m++)
        #pragma unroll
        for (int n=0;n<4;n++)
          acc[m][n] = __builtin_amdgcn_mfma_f32_16x16x32_bf16(af[m], bfr[n], acc[m][n], 0,0,0);
    }
    __syncthreads();
  }
  // epilogue
  #pragma unroll
  for (int n=0;n<4;n++){
    int col = bn0 + wc*64 + n*16 + (lane & 15);
    bool isq = col < 1024;
    float bias = isq ? bq[col] : bv[col - 1024];
    #pragma unroll
    for (int m=0;m<4;m++){
      #pragma unroll
      for (int j=0;j<4;j++){
        int row = bm0 + wr*64 + m*16 + (lane>>4)*4 + j;
        float val = acc[m][n][j] + bias;
        if (isq){
          int d = col & 63;
          int scol = (col & ~63) | ((((d>>3) ^ (row & 7)) & 7) << 3) | (d & 7);
          q_bf[(size_t)row*1024 + scol] = f2bf(val);
        } else if (row < N_NODES){
          xv_out[(size_t)row*1024 + (col - 1024)] = val;
        }
      }
    }
  }
}

// ---------------- attn passes ----------------
// PHASE 0: colsumA = sum_n Q0 ; v_sl[nb&7] += sigmoid(attn)^T @ xv   (per head)
// PHASE 1: w=1/(128*cs_in); u=1/(50000*sum_r Q0*w); cs_out += sum_n u*Q0
// PHASE 2: w3,u3 -> cons = 50000*u3*Q0*w3 ; out = sig(a)*xv + sig(b)*(cons@v)
template<int PHASE>
__global__ __launch_bounds__(256) void k_attn(
    const ushort_t* __restrict__ q_bf, const ushort_t* __restrict__ key_bf,
    const float* __restrict__ node_index, const float* __restrict__ Wb,
    const float* __restrict__ bb, const float* __restrict__ colsum_in,
    float* __restrict__ colsum_out, float* __restrict__ v_ws,
    float* xv_out,   // f32 xv (aliases final out)
    const float* __restrict__ alpha, const float* __restrict__ beta)
{
  extern __shared__ char smem[];
  ushort_t* q_lds   = (ushort_t*)(smem);          // 64x64 bf16 (8KB)
  ushort_t* key_lds = (ushort_t*)(smem + 8192);   // 128x64 bf16 (16KB)
  float* ni_lds  = (float*)(smem + 24576);        // 64x4
  float* wb_lds  = (float*)(smem + 25600);        // 128x5
  float* red_lds = (float*)(smem + 28160);        // 2 x [4][64]
  float* col_acc = (float*)(smem + 30208);        // 128
  float* w_lds   = (float*)(smem + 30720);        // 128
  ushort_t* sigT     = (ushort_t*)(smem + 31232); // PHASE0: 128x72 bf16
  ushort_t* xvT      = (ushort_t*)(smem + 31232 + 18432); // PHASE0: 64x72 bf16
  ushort_t* cons_lds = (ushort_t*)(smem + 31232); // PHASE2: 64x128 bf16 (swz)
  ushort_t* vT       = (ushort_t*)(smem + 31232 + 16384); // PHASE2: 64x128 bf16 (swz)
  float* out_lds = (float*)(smem);                // PHASE2: 64x68 f32 (over q/key)

  const int tid = threadIdx.x, lane = tid & 63, wid = tid >> 6;
  const int h  = blockIdx.x & 15;
  const int nb = blockIdx.x >> 4;
  const int i0 = nb * 64;

  // ---- stage ----
  #pragma unroll
  for (int it = 0; it < 2; ++it){
    int chunk = it*256 + tid;
    int r = chunk >> 3, c = chunk & 7;
    gload_lds16(q_bf + (size_t)(i0 + r)*1024 + h*64 + c*8, q_lds + it*2048 + tid*8);
  }
  #pragma unroll
  for (int it = 0; it < 4; ++it){
    int chunk = it*256 + tid;
    int r = chunk >> 3, c = chunk & 7;
    gload_lds16(key_bf + (size_t)h*8192 + r*64 + c*8, key_lds + it*2048 + tid*8);
  }
  { int r = tid >> 2, c = tid & 3;
    ni_lds[tid] = (i0 + r < N_NODES) ? node_index[(size_t)(i0 + r)*4 + c] : 0.f; }
  if (tid < 128){
    #pragma unroll
    for (int c=0;c<4;c++) wb_lds[tid*5+c] = Wb[(size_t)(h*128 + tid)*4 + c];
    wb_lds[tid*5+4] = bb[h*128 + tid];
    if (PHASE >= 1) w_lds[tid] = 1.f / (128.f * colsum_in[h*128 + tid]);
  }
  __syncthreads();

  // ---- attn^T = key @ q^T / 8 + bias^T ; element (r, nn) ----
  f32x4 acc[2][4];
  for (int m=0;m<2;m++) for (int n=0;n<4;n++) acc[m][n] = (f32x4){0.f,0.f,0.f,0.f};
  #pragma unroll
  for (int kk = 0; kk < 2; ++kk){
    short8 kf[2];
    #pragma unroll
    for (int m=0;m<2;m++) kf[m] = frag64(key_lds, wid*32 + m*16 + (lane&15), kk, lane);
    #pragma unroll
    for (int n=0;n<4;n++){
      short8 qf = frag64(q_lds, n*16 + (lane&15), kk, lane);
      #pragma unroll
      for (int m=0;m<2;m++)
        acc[m][n] = __builtin_amdgcn_mfma_f32_16x16x32_bf16(kf[m], qf, acc[m][n], 0,0,0);
    }
  }

  float nif[4][4];
  #pragma unroll
  for (int n=0;n<4;n++){
    int nn = n*16 + (lane&15);
    #pragma unroll
    for (int c=0;c<4;c++) nif[n][c] = ni_lds[nn*4+c];
  }
  float a[2][4][4];
  #pragma unroll
  for (int m=0;m<2;m++){
    #pragma unroll
    for (int j=0;j<4;j++){
      int r = wid*32 + m*16 + (lane>>4)*4 + j;
      float w0 = wb_lds[r*5+0], w1 = wb_lds[r*5+1];
      float w2 = wb_lds[r*5+2], w3 = wb_lds[r*5+3], w4 = wb_lds[r*5+4];
      #pragma unroll
      for (int n=0;n<4;n++){
        float b = w4 + w0*nif[n][0] + w1*nif[n][1] + w2*nif[n][2] + w3*nif[n][3];
        a[m][n][j] = acc[m][n][j]*0.125f + b;
      }
    }
  }

  float vmask[4];
  #pragma unroll
  for (int n=0;n<4;n++) vmask[n] = (i0 + n*16 + (lane&15) < N_NODES) ? 1.f : 0.f;

  if constexpr (PHASE == 0){
    // sigmoid -> sigT (A operand, [r][nn] pad-72), masked
    #pragma unroll
    for (int m=0;m<2;m++) for (int n=0;n<4;n++) for (int j=0;j<4;j++){
      int r  = wid*32 + m*16 + (lane>>4)*4 + j;
      int nn = n*16 + (lane&15);
      float sg = vmask[n] / (1.f + __expf(-a[m][n][j]));
      sigT[r*72 + nn] = f2bf(sg);
    }
    // xv^T -> xvT ([d][nn] pad-72), from f32 xv
    { int d = tid & 63, q4 = tid >> 6;
      #pragma unroll
      for (int i=0;i<16;i++){
        int nn = q4*16 + i;
        int row = i0 + nn;
        float v = (row < N_NODES) ? xv_out[(size_t)row*1024 + h*64 + d] : 0.f;
        xvT[d*72 + nn] = f2bf(v);
      }
    }
  }
  if constexpr (PHASE == 2){
    // v^T -> vT ([d][r=128] chunk-swizzled by d&7)
    int r = tid >> 1, dh = (tid & 1)*32;
    #pragma unroll
    for (int i=0;i<32;i++){
      int d = dh + i;
      float v = v_ws[((size_t)r*16 + h)*64 + d];
      vT[d*128 + ((r>>3) ^ (d&7))*8 + (r&7)] = f2bf(v);
    }
  }

  // ---- softmax over r (columns of attn^T) ----
  float pm[4];
  #pragma unroll
  for (int n=0;n<4;n++){
    float m0 = a[0][n][0];
    #pragma unroll
    for (int m=0;m<2;m++) for (int j=0;j<4;j++) m0 = fmaxf(m0, a[m][n][j]);
    m0 = fmaxf(m0, __shfl_xor(m0, 16));
    m0 = fmaxf(m0, __shfl_xor(m0, 32));
    pm[n] = m0;
  }
  if (lane < 16){
    #pragma unroll
    for (int n=0;n<4;n++) red_lds[wid*64 + n*16 + lane] = pm[n];
  }
  __syncthreads();   // also covers sigT/xvT/vT writes

  float mnn[4], snn[4];
  #pragma unroll
  for (int n=0;n<4;n++){
    int nn = n*16 + (lane&15);
    float m0 = red_lds[nn];
    m0 = fmaxf(m0, red_lds[64+nn]); m0 = fmaxf(m0, red_lds[128+nn]); m0 = fmaxf(m0, red_lds[192+nn]);
    mnn[n] = m0;
  }
  #pragma unroll
  for (int n=0;n<4;n++){
    float s = 0.f;
    #pragma unroll
    for (int m=0;m<2;m++) for (int j=0;j<4;j++){
      float e = __expf(a[m][n][j] - mnn[n]);
      a[m][n][j] = e; s += e;
    }
    s += __shfl_xor(s, 16); s += __shfl_xor(s, 32);
    snn[n] = s;
  }
  if (lane < 16){
    #pragma unroll
    for (int n=0;n<4;n++) red_lds[256 + wid*64 + n*16 + lane] = snn[n];
  }

  if constexpr (PHASE == 0){
    // v-acc MFMA: D[r][d] = sum_nn sigT[r][nn] * xvT[d][nn]
    f32x4 vac[2][4];
    for (int m=0;m<2;m++) for (int n=0;n<4;n++) vac[m][n] = (f32x4){0.f,0.f,0.f,0.f};
    #pragma unroll
    for (int kk=0;kk<2;kk++){
      short8 sa[2];
      #pragma unroll
      for (int m=0;m<2;m++) sa[m] = fragp72(sigT, wid*32 + m*16 + (lane&15), kk, lane);
      #pragma unroll
      for (int n=0;n<4;n++){
        short8 xf = fragp72(xvT, n*16 + (lane&15), kk, lane);
        #pragma unroll
        for (int m=0;m<2;m++)
          vac[m][n] = __builtin_amdgcn_mfma_f32_16x16x32_bf16(sa[m], xf, vac[m][n], 0,0,0);
      }
    }
    float* vdst = v_ws + (size_t)(nb & 7)*131072;
    #pragma unroll
    for (int m=0;m<2;m++) for (int n=0;n<4;n++) for (int j=0;j<4;j++){
      int r = wid*32 + m*16 + (lane>>4)*4 + j;
      int d = n*16 + (lane&15);
      atomicAdd(&vdst[((size_t)r*16 + h)*64 + d], vac[m][n][j]);
    }
  }
  __syncthreads();

  #pragma unroll
  for (int n=0;n<4;n++){
    int nn = n*16 + (lane&15);
    snn[n] = red_lds[256+nn] + red_lds[256+64+nn] + red_lds[256+128+nn] + red_lds[256+192+nn];
  }
  // Q0 = exp(20 * softmax)
  #pragma unroll
  for (int n=0;n<4;n++){
    float inv = 20.f / snn[n];
    #pragma unroll
    for (int m=0;m<2;m++) for (int j=0;j<4;j++)
      a[m][n][j] = __expf(a[m][n][j] * inv);
  }

  float uval[4];
  if constexpr (PHASE >= 1){
    #pragma unroll
    for (int n=0;n<4;n++){
      float s = 0.f;
      #pragma unroll
      for (int m=0;m<2;m++){
        #pragma unroll
        for (int j=0;j<4;j++){
          int r = wid*32 + m*16 + (lane>>4)*4 + j;
          s += a[m][n][j] * w_lds[r];
        }
      }
      s += __shfl_xor(s, 16); s += __shfl_xor(s, 32);
      uval[n] = s;
    }
    if (lane < 16){
      #pragma unroll
      for (int n=0;n<4;n++) red_lds[wid*64 + n*16 + lane] = uval[n];
    }
    __syncthreads();
    #pragma unroll
    for (int n=0;n<4;n++){
      int nn = n*16 + (lane&15);
      float s = red_lds[nn] + red_lds[64+nn] + red_lds[128+nn] + red_lds[192+nn];
      uval[n] = 1.f / (50000.f * s);
    }
  }

  if constexpr (PHASE <= 1){
    float cs[2][4];
    #pragma unroll
    for (int m=0;m<2;m++){
      #pragma unroll
      for (int j=0;j<4;j++){
        float s = 0.f;
        #pragma unroll
        for (int n=0;n<4;n++){
          float t = a[m][n][j] * vmask[n];
          if (PHASE == 1) t *= uval[n];
          s += t;
        }
        s += __shfl_xor(s, 1); s += __shfl_xor(s, 2);
        s += __shfl_xor(s, 4); s += __shfl_xor(s, 8);
        cs[m][j] = s;
      }
    }
    if ((lane & 15) == 0){
      #pragma unroll
      for (int m=0;m<2;m++) for (int j=0;j<4;j++){
        int r = wid*32 + m*16 + (lane>>4)*4 + j;
        col_acc[r] = cs[m][j];
      }
    }
    __syncthreads();
    if (tid < 128) atomicAdd(&colsum_out[h*128 + tid], col_acc[tid]);
  }

  if constexpr (PHASE == 2){
    // cons[nn][r] = 50000 * u3[nn] * Q0 * w3[r]  (chunk-swizzled by nn&7)
    #pragma unroll
    for (int m=0;m<2;m++) for (int n=0;n<4;n++) for (int j=0;j<4;j++){
      int r  = wid*32 + m*16 + (lane>>4)*4 + j;
      int nn = n*16 + (lane&15);
      float cv = 50000.f * uval[n] * a[m][n][j] * w_lds[r];
      cons_lds[nn*128 + ((r>>3) ^ (nn&7))*8 + (r&7)] = f2bf(cv);
    }
    __syncthreads();
    // v_final^T[d][nn] = sum_r vT[d][r] * cons[nn][r]
    f32x4 oac[4];
    for (int n=0;n<4;n++) oac[n] = (f32x4){0.f,0.f,0.f,0.f};
    #pragma unroll
    for (int kk=0;kk<4;kk++){
      short8 va = frag128(vT, wid*16 + (lane&15), kk, lane);
      #pragma unroll
      for (int n=0;n<4;n++){
        short8 cf = frag128(cons_lds, n*16 + (lane&15), kk, lane);
        oac[n] = __builtin_amdgcn_mfma_f32_16x16x32_bf16(va, cf, oac[n], 0,0,0);
      }
    }
    #pragma unroll
    for (int n=0;n<4;n++) for (int j=0;j<4;j++){
      int d  = wid*16 + (lane>>4)*4 + j;
      int nn = n*16 + (lane&15);
      out_lds[nn*68 + d] = oac[n][j];
    }
    __syncthreads();
    float sa = 1.f/(1.f + __expf(-alpha[h]));
    float sb = 1.f/(1.f + __expf(-beta[h]));
    int nn = tid >> 2, d0 = (tid & 3)*16;
    if (i0 + nn < N_NODES){
      #pragma unroll
      for (int g=0; g<4; ++g){
        float4 vf = *(const float4*)(out_lds + nn*68 + d0 + g*4);
        float4 xf = *(const float4*)(xv_out + (size_t)(i0+nn)*1024 + h*64 + d0 + g*4);
        float4 o;
        o.x = sa*xf.x + sb*vf.x;
        o.y = sa*xf.y + sb*vf.y;
        o.z = sa*xf.z + sb*vf.z;
        o.w = sa*xf.w + sb*vf.w;
        *(float4*)(xv_out + (size_t)(i0+nn)*1024 + h*64 + d0 + g*4) = o;
      }
    }
  }
}

extern "C" void kernel_launch(void* const* d_in, const int* in_sizes, int n_in,
                              void* d_out, int out_size, void* d_ws, size_t ws_size,
                              hipStream_t stream){
  const float* x     = (const float*)d_in[0];
  const float* ni    = (const float*)d_in[1];
  const float* Wq    = (const float*)d_in[2];
  const float* bq    = (const float*)d_in[3];
  const float* keyp  = (const float*)d_in[4];
  const float* Wv    = (const float*)d_in[5];
  const float* bv    = (const float*)d_in[6];
  const float* alpha = (const float*)d_in[7];
  const float* beta  = (const float*)d_in[8];
  const float* Wb    = (const float*)d_in[9];
  const float* bb    = (const float*)d_in[10];
  float* out = (float*)d_out;

  char* ws = (char*)d_ws;
  ushort_t* x_bf   = (ushort_t*)(ws);                     // MPAD*1024 bf16
  ushort_t* q_bf   = (ushort_t*)(ws + 102498304);         // MPAD*1024 bf16
  ushort_t* w_bf   = (ushort_t*)(ws + 204996608);         // 2048*1024 bf16
  ushort_t* key_bf = (ushort_t*)(ws + 209190912);         // 16*128*64 bf16
  float*    v_sl   = (float*)(ws + 209453056);            // 8*131072 f32
  float*    v_fin  = (float*)(ws + 213647360);            // 131072 f32
  float*    cs     = (float*)(ws + 214171648);            // 3*2048 f32

  k_zero<<<dim3((8*131072 + 6144 + 255)/256), 256, 0, stream>>>(v_sl, 8*131072 + 6144);
  k_prep_x<<<dim3(25000), 256, 0, stream>>>(x, x_bf);
  k_prep_w<<<dim3(2048*1024/256), 256, 0, stream>>>(Wq, Wv, w_bf);
  k_prep_key<<<dim3(HEAD*KV*HD/256), 256, 0, stream>>>(keyp, key_bf);
  k_gemm<<<dim3(6256), 256, 0, stream>>>(x_bf, w_bf, bq, bv, q_bf, out);

  dim3 ag(782*16);
  k_attn<0><<<ag, 256, 58880, stream>>>(q_bf, key_bf, ni, Wb, bb, nullptr,  cs,      v_sl,  out, alpha, beta);
  k_vreduce<<<dim3(512), 256, 0, stream>>>(v_sl, v_fin);
  k_attn<1><<<ag, 256, 31232, stream>>>(q_bf, key_bf, ni, Wb, bb, cs,       cs+2048, v_fin, out, alpha, beta);
  k_attn<1><<<ag, 256, 31232, stream>>>(q_bf, key_bf, ni, Wb, bb, cs+2048,  cs+4096, v_fin, out, alpha, beta);
  k_attn<2><<<ag, 256, 64000, stream>>>(q_bf, key_bf, ni, Wb, bb, cs+4096,  nullptr, v_fin, out, alpha, beta);
}

// Round 3
// 1041.822 us; speedup vs baseline: 1.3589x; 1.2184x over previous
//
#include <hip/hip_runtime.h>

#define N_NODES 50000
#define MPAD    50048   // 391*128
#define DIM     1024
#define HEAD    16
#define KV      128
#define HD      64
#define NGRP    98      // ceil(MPAD/512)

typedef unsigned short ushort_t;
typedef short short8 __attribute__((ext_vector_type(8)));
typedef float f32x4 __attribute__((ext_vector_type(4)));

__device__ inline unsigned short f2bf(float f){
  union { float f; unsigned u; } v; v.f = f;
  unsigned u = v.u;
  unsigned r = (u + 0x7FFFu + ((u >> 16) & 1u)) >> 16;
  return (unsigned short)r;
}
__device__ inline float bf2f(unsigned short u){
  union { unsigned u; float f; } v; v.u = ((unsigned)u) << 16; return v.f;
}

__device__ inline void gload_lds16(const void* g, void* l){
  __builtin_amdgcn_global_load_lds(
      (const __attribute__((address_space(1))) void*)g,
      (__attribute__((address_space(3))) void*)l, 16, 0, 0);
}

// fragment loads: row-major [*][64] or [*][128] bf16 LDS tile, 16B-chunk XOR-swizzled by (row&7)
__device__ inline short8 frag64(const ushort_t* lds, int row, int kk, int lane){
  int c  = kk*4 + (lane >> 4);
  int cc = c ^ (row & 7);
  return *(const short8*)(lds + row*64 + cc*8);
}
__device__ inline short8 frag128(const ushort_t* lds, int row, int kk, int lane){
  int c  = kk*4 + (lane >> 4);
  int cc = c ^ (row & 7);
  return *(const short8*)(lds + row*128 + cc*8);
}

// ---------------- prep kernels ----------------
__global__ void k_zero(float* p, int n){
  int i = blockIdx.x*256 + threadIdx.x;
  if (i < n) p[i] = 0.f;
}

// x fp32 -> bf16, 16B-chunk swizzle keyed by row&7 (for global_load_lds staging)
__global__ void k_prep_x(const float* __restrict__ x, ushort_t* __restrict__ x_bf){
  int idx = blockIdx.x*256 + threadIdx.x;   // N_NODES*128 chunks of 8
  int row = idx >> 7, c = idx & 127;
  const float4* s = (const float4*)(x + (size_t)row*1024 + c*8);
  float4 f0 = s[0], f1 = s[1];
  short8 v;
  v[0]=(short)f2bf(f0.x); v[1]=(short)f2bf(f0.y); v[2]=(short)f2bf(f0.z); v[3]=(short)f2bf(f0.w);
  v[4]=(short)f2bf(f1.x); v[5]=(short)f2bf(f1.y); v[6]=(short)f2bf(f1.z); v[7]=(short)f2bf(f1.w);
  int sc = (c & ~7) | ((c ^ row) & 7);
  *(short8*)(x_bf + (size_t)row*1024 + sc*8) = v;
}

// W concat (rows 0..1023 = Wq, 1024..2047 = Wv), bf16, 16B-chunk swizzle keyed by row&7
__global__ void k_prep_w(const float* __restrict__ Wq, const float* __restrict__ Wv,
                         ushort_t* __restrict__ w_bf){
  int idx = blockIdx.x*256 + threadIdx.x;   // 2048*1024
  int j = idx >> 10, k = idx & 1023;
  float v = (j < 1024) ? Wq[idx] : Wv[(size_t)(j-1024)*1024 + k];
  int d = k & 63;
  int scol = (k & ~63) | ((((d>>3) ^ (j & 7)) & 7) << 3) | (d & 7);
  w_bf[(size_t)j*1024 + scol] = f2bf(v);
}

// key_bf[h][r][swz(d, r)]  from key_p[r][h][d]
__global__ void k_prep_key(const float* __restrict__ key_p, ushort_t* __restrict__ key_bf){
  int idx = blockIdx.x*256 + threadIdx.x;   // 16*128*64
  int h = idx >> 13, rem = idx & 8191;
  int r = rem >> 6, d = rem & 63;
  float v = key_p[(size_t)(r*HEAD + h)*HD + d];
  int pos = ((((d>>3) ^ (r & 7)) & 7) << 3) | (d & 7);
  key_bf[(size_t)h*8192 + r*64 + pos] = f2bf(v);
}

// sum the NGRP v-slices
__global__ void k_vreduce(const float* __restrict__ vp, float* __restrict__ vout){
  int i = blockIdx.x*256 + threadIdx.x;   // 131072
  float s = 0.f;
  for (int gg = 0; gg < NGRP; ++gg) s += vp[(size_t)gg*131072 + i];
  vout[i] = s;
}

// ---------------- big GEMM: [q|xv] = x @ [Wq;Wv]^T + [bq;bv] ----------------
__global__ __launch_bounds__(256) void k_gemm(const ushort_t* __restrict__ x_bf,
    const ushort_t* __restrict__ w_bf, const float* __restrict__ bq,
    const float* __restrict__ bv, ushort_t* __restrict__ q_bf, float* xv_out){
  __shared__ ushort_t a_lds[128*64];
  __shared__ ushort_t b_lds[128*64];
  const int tid = threadIdx.x, lane = tid & 63;
  const int wid = tid >> 6, wr = wid >> 1, wc = wid & 1;
  int b = blockIdx.x;
  int wg = (b & 7)*782 + (b >> 3);
  const int bm0 = (wg >> 4) * 128, bn0 = (wg & 15) * 128;

  f32x4 acc[4][4];
  for (int m=0;m<4;m++) for (int n=0;n<4;n++) acc[m][n] = (f32x4){0.f,0.f,0.f,0.f};

  for (int kt = 0; kt < 16; ++kt){
    const int k0 = kt * 64;
    #pragma unroll
    for (int it = 0; it < 4; ++it){
      int chunk = it*256 + tid;
      int r = chunk >> 3, c = chunk & 7;
      gload_lds16(x_bf + (size_t)(bm0 + r)*1024 + k0 + c*8, a_lds + chunk*8);
    }
    #pragma unroll
    for (int it = 0; it < 4; ++it){
      int chunk = it*256 + tid;
      int r = chunk >> 3, c = chunk & 7;
      gload_lds16(w_bf + (size_t)(bn0 + r)*1024 + k0 + c*8, b_lds + chunk*8);
    }
    __syncthreads();
    #pragma unroll
    for (int kk = 0; kk < 2; ++kk){
      short8 af[4], bfr[4];
      #pragma unroll
      for (int m=0;m<4;m++) af[m]  = frag64(a_lds, wr*64 + m*16 + (lane&15), kk, lane);
      #pragma unroll
      for (int n=0;n<4;n++) bfr[n] = frag64(b_lds, wc*64 + n*16 + (lane&15), kk, lane);
      #pragma unroll
      for (int m=0;m<4;m++)
        #pragma unroll
        for (int n=0;n<4;n++)
          acc[m][n] = __builtin_amdgcn_mfma_f32_16x16x32_bf16(af[m], bfr[n], acc[m][n], 0,0,0);
    }
    __syncthreads();
  }
  #pragma unroll
  for (int n=0;n<4;n++){
    int col = bn0 + wc*64 + n*16 + (lane & 15);
    bool isq = col < 1024;
    float bias = isq ? bq[col] : bv[col - 1024];
    #pragma unroll
    for (int m=0;m<4;m++){
      #pragma unroll
      for (int j=0;j<4;j++){
        int row = bm0 + wr*64 + m*16 + (lane>>4)*4 + j;
        float val = acc[m][n][j] + bias;
        if (isq){
          int d = col & 63;
          int scol = (col & ~63) | ((((d>>3) ^ (row & 7)) & 7) << 3) | (d & 7);
          q_bf[(size_t)row*1024 + scol] = f2bf(val);
        } else if (row < N_NODES){
          xv_out[(size_t)row*1024 + (col - 1024)] = val;
        }
      }
    }
  }
}

// ---------------- attn passes (looped: 8 node-tiles of 64 per block) ----------------
// PHASE 0: colsumA = sum_n Q0 ; v_part[g] = sigmoid(attn)^T @ xv (reg-accum, plain store)
// PHASE 1: w=1/(128*cs_in); u=1/(50000*sum_r Q0*w); cs_out += sum_n u*Q0
// PHASE 2: w3,u3 -> cons = 50000*u3*Q0*w3 ; out = sig(a)*xv + sig(b)*(cons@v)
template<int PHASE>
__global__ __launch_bounds__(256) void k_attn(
    const ushort_t* __restrict__ q_bf, const ushort_t* __restrict__ key_bf,
    const float* __restrict__ node_index, const float* __restrict__ Wb,
    const float* __restrict__ bb, const float* __restrict__ colsum_in,
    float* __restrict__ colsum_out, const float* __restrict__ v_fin,
    float* __restrict__ v_part, float* xv_out,
    const float* __restrict__ alpha, const float* __restrict__ beta)
{
  constexpr int QB    = (PHASE == 2) ? 1 : 2;
  constexpr int O_Q   = 0;                     // QB x 64x64 bf16 (8KB each)
  constexpr int O_KEY = O_Q + QB*8192;         // 128x64 bf16 (16KB)
  constexpr int O_NI  = O_KEY + 16384;         // QB x 256 f32
  constexpr int O_WB  = O_NI + QB*1024;        // 128x5 f32
  constexpr int O_RED = O_WB + 2560;           // 512 f32
  constexpr int O_COL = O_RED + 2048;          // 128 f32
  constexpr int O_W   = O_COL + 512;           // 128 f32
  constexpr int O_X1  = O_W + 512;             // P0: sigT 128x64 swz ; P2: vT 64x[128] swz
  constexpr int O_X2  = O_X1 + 16384;          // P0: xvT 64x64 swz ; P2: cons(bf16 64x128)/out(f32 64x68)

  extern __shared__ char smem[];
  ushort_t* q_lds   = (ushort_t*)(smem + O_Q);
  ushort_t* key_lds = (ushort_t*)(smem + O_KEY);
  float* ni_lds  = (float*)(smem + O_NI);
  float* wb_lds  = (float*)(smem + O_WB);
  float* red_lds = (float*)(smem + O_RED);
  float* col_acc = (float*)(smem + O_COL);
  float* w_lds   = (float*)(smem + O_W);
  ushort_t* sigT     = (ushort_t*)(smem + O_X1);
  ushort_t* xvT      = (ushort_t*)(smem + O_X2);
  ushort_t* vT       = (ushort_t*)(smem + O_X1);
  ushort_t* cons_lds = (ushort_t*)(smem + O_X2);
  float*    out_lds  = (float*)(smem + O_X2);

  const int tid = threadIdx.x, lane = tid & 63, wid = tid >> 6;
  const int h    = blockIdx.x & 15;
  const int g    = blockIdx.x >> 4;
  const int base = g * 512;
  int NT = (MPAD - base) >> 6; if (NT > 8) NT = 8;

  // ---- prologue staging ----
  #pragma unroll
  for (int it = 0; it < 4; ++it){
    int chunk = it*256 + tid;
    gload_lds16(key_bf + (size_t)h*8192 + chunk*8, key_lds + chunk*8);
  }
  #pragma unroll
  for (int it = 0; it < 2; ++it){
    int chunk = it*256 + tid;
    int r = chunk >> 3, c = chunk & 7;
    gload_lds16(q_bf + (size_t)(base + r)*1024 + h*64 + c*8, q_lds + chunk*8);
  }
  { int r = tid >> 2, c = tid & 3;
    ni_lds[tid] = (base + r < N_NODES) ? node_index[(size_t)(base + r)*4 + c] : 0.f; }
  if (tid < 128){
    #pragma unroll
    for (int c=0;c<4;c++) wb_lds[tid*5+c] = Wb[(size_t)(h*128 + tid)*4 + c];
    wb_lds[tid*5+4] = bb[h*128 + tid];
    if (PHASE >= 1) w_lds[tid] = 1.f / (128.f * colsum_in[h*128 + tid]);
    if (PHASE <= 1) col_acc[tid] = 0.f;
  }
  if constexpr (PHASE == 2){
    int r = tid >> 1, dh = (tid & 1)*32;
    #pragma unroll
    for (int i=0;i<32;i++){
      int d = dh + i;
      vT[d*128 + ((r>>3) ^ (d&7))*8 + (r&7)] = f2bf(v_fin[((size_t)r*16 + h)*64 + d]);
    }
  }
  float xvr[16], xvn[16];
  if constexpr (PHASE == 0){
    int d = tid & 63, q4 = tid >> 6;
    #pragma unroll
    for (int i=0;i<16;i++){
      int row = base + q4*16 + i;
      xvr[i] = (row < N_NODES) ? xv_out[(size_t)row*1024 + h*64 + d] : 0.f;
    }
  }
  f32x4 vac[2][4];
  if constexpr (PHASE == 0)
    for (int m=0;m<2;m++) for (int n=0;n<4;n++) vac[m][n] = (f32x4){0.f,0.f,0.f,0.f};

  __syncthreads();

  // ---- main loop over node tiles ----
  for (int t = 0; t < NT; ++t){
    const int i0  = base + t*64;
    const int cur = t & 1;
    const ushort_t* qb  = q_lds  + ((QB==2) ? cur*4096 : 0);
    const float*    nib = ni_lds + ((QB==2) ? cur*256  : 0);
    float ni_next = 0.f;

    if constexpr (QB == 2){
      if (t+1 < NT){
        int i1 = i0 + 64;
        #pragma unroll
        for (int it = 0; it < 2; ++it){
          int chunk = it*256 + tid;
          int r = chunk >> 3, c = chunk & 7;
          gload_lds16(q_bf + (size_t)(i1 + r)*1024 + h*64 + c*8,
                      q_lds + (cur^1)*4096 + chunk*8);
        }
        int r = tid >> 2, c = tid & 3;
        ni_next = (i0 + 64 + r < N_NODES) ? node_index[(size_t)(i0+64+r)*4 + c] : 0.f;
      }
    } else {
      if (t+1 < NT){
        int r = tid >> 2, c = tid & 3;
        ni_next = (i0 + 64 + r < N_NODES) ? node_index[(size_t)(i0+64+r)*4 + c] : 0.f;
      }
    }
    if constexpr (PHASE == 0){
      if (t+1 < NT){
        int d = tid & 63, q4 = tid >> 6;
        #pragma unroll
        for (int i=0;i<16;i++){
          int row = i0 + 64 + q4*16 + i;
          xvn[i] = (row < N_NODES) ? xv_out[(size_t)row*1024 + h*64 + d] : 0.f;
        }
      }
    }

    // ---- attn^T = key @ q^T / 8 + bias^T ----
    f32x4 acc[2][4];
    for (int m=0;m<2;m++) for (int n=0;n<4;n++) acc[m][n] = (f32x4){0.f,0.f,0.f,0.f};
    #pragma unroll
    for (int kk = 0; kk < 2; ++kk){
      short8 kf[2];
      #pragma unroll
      for (int m=0;m<2;m++) kf[m] = frag64(key_lds, wid*32 + m*16 + (lane&15), kk, lane);
      #pragma unroll
      for (int n=0;n<4;n++){
        short8 qf = frag64(qb, n*16 + (lane&15), kk, lane);
        #pragma unroll
        for (int m=0;m<2;m++)
          acc[m][n] = __builtin_amdgcn_mfma_f32_16x16x32_bf16(kf[m], qf, acc[m][n], 0,0,0);
      }
    }

    float nif[4][4];
    #pragma unroll
    for (int n=0;n<4;n++){
      int nn = n*16 + (lane&15);
      #pragma unroll
      for (int c=0;c<4;c++) nif[n][c] = nib[nn*4+c];
    }
    float a[2][4][4];
    #pragma unroll
    for (int m=0;m<2;m++){
      #pragma unroll
      for (int j=0;j<4;j++){
        int r = wid*32 + m*16 + (lane>>4)*4 + j;
        float w0 = wb_lds[r*5+0], w1 = wb_lds[r*5+1];
        float w2 = wb_lds[r*5+2], w3 = wb_lds[r*5+3], w4 = wb_lds[r*5+4];
        #pragma unroll
        for (int n=0;n<4;n++){
          float b = w4 + w0*nif[n][0] + w1*nif[n][1] + w2*nif[n][2] + w3*nif[n][3];
          a[m][n][j] = acc[m][n][j]*0.125f + b;
        }
      }
    }

    float vmask[4];
    #pragma unroll
    for (int n=0;n<4;n++) vmask[n] = (i0 + n*16 + (lane&15) < N_NODES) ? 1.f : 0.f;

    if constexpr (PHASE == 0){
      // sigmoid -> sigT [r][nn] swizzled, masked
      #pragma unroll
      for (int m=0;m<2;m++) for (int n=0;n<4;n++) for (int j=0;j<4;j++){
        int r  = wid*32 + m*16 + (lane>>4)*4 + j;
        int nn = n*16 + (lane&15);
        float sg = vmask[n] / (1.f + __expf(-a[m][n][j]));
        sigT[r*64 + ((((nn>>3) ^ (r&7)) & 7) << 3) + (nn&7)] = f2bf(sg);
      }
      // xv^T -> xvT [d][nn] swizzled (from prefetched regs)
      { int d = tid & 63, q4 = tid >> 6;
        #pragma unroll
        for (int i=0;i<16;i++){
          int nn = q4*16 + i;
          xvT[d*64 + ((((nn>>3) ^ (d&7)) & 7) << 3) + (nn&7)] = f2bf(xvr[i]);
        }
      }
    }

    // ---- softmax over r ----
    float pm[4];
    #pragma unroll
    for (int n=0;n<4;n++){
      float m0 = a[0][n][0];
      #pragma unroll
      for (int m=0;m<2;m++) for (int j=0;j<4;j++) m0 = fmaxf(m0, a[m][n][j]);
      m0 = fmaxf(m0, __shfl_xor(m0, 16));
      m0 = fmaxf(m0, __shfl_xor(m0, 32));
      pm[n] = m0;
    }
    if (lane < 16){
      #pragma unroll
      for (int n=0;n<4;n++) red_lds[wid*64 + n*16 + lane] = pm[n];
    }
    __syncthreads();   // B: publishes red-max + sigT/xvT

    if constexpr (QB == 1){
      if (t+1 < NT){
        int i1 = i0 + 64;
        #pragma unroll
        for (int it = 0; it < 2; ++it){
          int chunk = it*256 + tid;
          int r = chunk >> 3, c = chunk & 7;
          gload_lds16(q_bf + (size_t)(i1 + r)*1024 + h*64 + c*8, q_lds + chunk*8);
        }
        ni_lds[tid] = ni_next;
      }
    }

    float mnn[4], snn[4];
    #pragma unroll
    for (int n=0;n<4;n++){
      int nn = n*16 + (lane&15);
      float m0 = red_lds[nn];
      m0 = fmaxf(m0, red_lds[64+nn]); m0 = fmaxf(m0, red_lds[128+nn]); m0 = fmaxf(m0, red_lds[192+nn]);
      mnn[n] = m0;
    }
    #pragma unroll
    for (int n=0;n<4;n++){
      float s = 0.f;
      #pragma unroll
      for (int m=0;m<2;m++) for (int j=0;j<4;j++){
        float e = __expf(a[m][n][j] - mnn[n]);
        a[m][n][j] = e; s += e;
      }
      s += __shfl_xor(s, 16); s += __shfl_xor(s, 32);
      snn[n] = s;
    }
    if (lane < 16){
      #pragma unroll
      for (int n=0;n<4;n++) red_lds[256 + wid*64 + n*16 + lane] = snn[n];
    }

    if constexpr (PHASE == 0){
      // vac += sigT @ xvT^T (accumulates across tiles)
      #pragma unroll
      for (int kk=0;kk<2;kk++){
        short8 sa[2];
        #pragma unroll
        for (int m=0;m<2;m++) sa[m] = frag64(sigT, wid*32 + m*16 + (lane&15), kk, lane);
        #pragma unroll
        for (int n=0;n<4;n++){
          short8 xf = frag64(xvT, n*16 + (lane&15), kk, lane);
          #pragma unroll
          for (int m=0;m<2;m++)
            vac[m][n] = __builtin_amdgcn_mfma_f32_16x16x32_bf16(sa[m], xf, vac[m][n], 0,0,0);
        }
      }
    }
    __syncthreads();   // C: publishes red-sum

    #pragma unroll
    for (int n=0;n<4;n++){
      int nn = n*16 + (lane&15);
      snn[n] = red_lds[256+nn] + red_lds[256+64+nn] + red_lds[256+128+nn] + red_lds[256+192+nn];
    }
    // Q0 = exp(20 * softmax)
    #pragma unroll
    for (int n=0;n<4;n++){
      float inv = 20.f / snn[n];
      #pragma unroll
      for (int m=0;m<2;m++) for (int j=0;j<4;j++)
        a[m][n][j] = __expf(a[m][n][j] * inv);
    }

    float uval[4];
    if constexpr (PHASE >= 1){
      #pragma unroll
      for (int n=0;n<4;n++){
        float s = 0.f;
        #pragma unroll
        for (int m=0;m<2;m++){
          #pragma unroll
          for (int j=0;j<4;j++){
            int r = wid*32 + m*16 + (lane>>4)*4 + j;
            s += a[m][n][j] * w_lds[r];
          }
        }
        s += __shfl_xor(s, 16); s += __shfl_xor(s, 32);
        uval[n] = s;
      }
      if (lane < 16){
        #pragma unroll
        for (int n=0;n<4;n++) red_lds[wid*64 + n*16 + lane] = uval[n];
      }
      __syncthreads();   // D
      #pragma unroll
      for (int n=0;n<4;n++){
        int nn = n*16 + (lane&15);
        float s = red_lds[nn] + red_lds[64+nn] + red_lds[128+nn] + red_lds[192+nn];
        uval[n] = 1.f / (50000.f * s);
      }
    }

    if constexpr (PHASE <= 1){
      float cs[2][4];
      #pragma unroll
      for (int m=0;m<2;m++){
        #pragma unroll
        for (int j=0;j<4;j++){
          float s = 0.f;
          #pragma unroll
          for (int n=0;n<4;n++){
            float tv = a[m][n][j] * vmask[n];
            if (PHASE == 1) tv *= uval[n];
            s += tv;
          }
          s += __shfl_xor(s, 1); s += __shfl_xor(s, 2);
          s += __shfl_xor(s, 4); s += __shfl_xor(s, 8);
          cs[m][j] = s;
        }
      }
      if ((lane & 15) == 0){
        #pragma unroll
        for (int m=0;m<2;m++) for (int j=0;j<4;j++){
          int r = wid*32 + m*16 + (lane>>4)*4 + j;
          col_acc[r] += cs[m][j];
        }
      }
    }

    if constexpr (PHASE == 2){
      #pragma unroll
      for (int m=0;m<2;m++) for (int n=0;n<4;n++) for (int j=0;j<4;j++){
        int r  = wid*32 + m*16 + (lane>>4)*4 + j;
        int nn = n*16 + (lane&15);
        float cv = 50000.f * uval[n] * a[m][n][j] * w_lds[r];
        cons_lds[nn*128 + ((r>>3) ^ (nn&7))*8 + (r&7)] = f2bf(cv);
      }
      __syncthreads();   // E: cons ready
      f32x4 oac[4];
      for (int n=0;n<4;n++) oac[n] = (f32x4){0.f,0.f,0.f,0.f};
      #pragma unroll
      for (int kk=0;kk<4;kk++){
        short8 va = frag128(vT, wid*16 + (lane&15), kk, lane);
        #pragma unroll
        for (int n=0;n<4;n++){
          short8 cf = frag128(cons_lds, n*16 + (lane&15), kk, lane);
          oac[n] = __builtin_amdgcn_mfma_f32_16x16x32_bf16(va, cf, oac[n], 0,0,0);
        }
      }
      __syncthreads();   // F: cons reads done -> reuse region as out_lds
      #pragma unroll
      for (int n=0;n<4;n++) for (int j=0;j<4;j++){
        int d  = wid*16 + (lane>>4)*4 + j;
        int nn = n*16 + (lane&15);
        out_lds[nn*68 + d] = oac[n][j];
      }
      __syncthreads();   // G (end-iter): publishes out_lds + q[t+1]
      float sa = 1.f/(1.f + __expf(-alpha[h]));
      float sb = 1.f/(1.f + __expf(-beta[h]));
      int nn = tid >> 2, d0 = (tid & 3)*16;
      if (i0 + nn < N_NODES){
        #pragma unroll
        for (int gq=0; gq<4; ++gq){
          float4 vf = *(const float4*)(out_lds + nn*68 + d0 + gq*4);
          float4 xf = *(const float4*)(xv_out + (size_t)(i0+nn)*1024 + h*64 + d0 + gq*4);
          float4 o;
          o.x = sa*xf.x + sb*vf.x;
          o.y = sa*xf.y + sb*vf.y;
          o.z = sa*xf.z + sb*vf.z;
          o.w = sa*xf.w + sb*vf.w;
          *(float4*)(xv_out + (size_t)(i0+nn)*1024 + h*64 + d0 + gq*4) = o;
        }
      }
    } else {
      if (t+1 < NT && QB == 2) ni_lds[(cur^1)*256 + tid] = ni_next;
      if constexpr (PHASE == 0){
        if (t+1 < NT){
          #pragma unroll
          for (int i=0;i<16;i++) xvr[i] = xvn[i];
        }
      }
      __syncthreads();   // end-iter: publishes q[t+1], ni[t+1]
    }
  }

  // ---- final flushes ----
  if constexpr (PHASE == 0){
    float* vdst = v_part + (size_t)g*131072;
    #pragma unroll
    for (int m=0;m<2;m++) for (int n=0;n<4;n++) for (int j=0;j<4;j++){
      int r = wid*32 + m*16 + (lane>>4)*4 + j;
      int d = n*16 + (lane&15);
      vdst[((size_t)r*16 + h)*64 + d] = vac[m][n][j];
    }
  }
  if constexpr (PHASE <= 1){
    if (tid < 128) atomicAdd(&colsum_out[h*128 + tid], col_acc[tid]);
  }
}

extern "C" void kernel_launch(void* const* d_in, const int* in_sizes, int n_in,
                              void* d_out, int out_size, void* d_ws, size_t ws_size,
                              hipStream_t stream){
  const float* x     = (const float*)d_in[0];
  const float* ni    = (const float*)d_in[1];
  const float* Wq    = (const float*)d_in[2];
  const float* bq    = (const float*)d_in[3];
  const float* keyp  = (const float*)d_in[4];
  const float* Wv    = (const float*)d_in[5];
  const float* bv    = (const float*)d_in[6];
  const float* alpha = (const float*)d_in[7];
  const float* beta  = (const float*)d_in[8];
  const float* Wb    = (const float*)d_in[9];
  const float* bb    = (const float*)d_in[10];
  float* out = (float*)d_out;

  char* ws = (char*)d_ws;
  ushort_t* x_bf   = (ushort_t*)(ws);                     // MPAD*1024 bf16 (dead after gemm)
  float*    v_part = (float*)(ws);                        // NGRP*131072 f32, overlays x_bf
  ushort_t* q_bf   = (ushort_t*)(ws + 102498304);         // MPAD*1024 bf16
  ushort_t* w_bf   = (ushort_t*)(ws + 204996608);         // 2048*1024 bf16
  ushort_t* key_bf = (ushort_t*)(ws + 209190912);         // 16*128*64 bf16
  float*    v_fin  = (float*)(ws + 209453056);            // 131072 f32
  float*    cs     = (float*)(ws + 209977344);            // 3*2048 f32

  k_zero<<<dim3(24), 256, 0, stream>>>(cs, 6144);
  k_prep_x<<<dim3(25000), 256, 0, stream>>>(x, x_bf);
  k_prep_w<<<dim3(2048*1024/256), 256, 0, stream>>>(Wq, Wv, w_bf);
  k_prep_key<<<dim3(HEAD*KV*HD/256), 256, 0, stream>>>(keyp, key_bf);
  k_gemm<<<dim3(6256), 256, 0, stream>>>(x_bf, w_bf, bq, bv, q_bf, out);

  dim3 ag(NGRP*16);
  k_attn<0><<<ag, 256, 65024, stream>>>(q_bf, key_bf, ni, Wb, bb, nullptr,  cs,      v_fin, v_part, out, alpha, beta);
  k_vreduce<<<dim3(512), 256, 0, stream>>>(v_part, v_fin);
  k_attn<1><<<ag, 256, 40448, stream>>>(q_bf, key_bf, ni, Wb, bb, cs,       cs+2048, v_fin, v_part, out, alpha, beta);
  k_attn<1><<<ag, 256, 40448, stream>>>(q_bf, key_bf, ni, Wb, bb, cs+2048,  cs+4096, v_fin, v_part, out, alpha, beta);
  k_attn<2><<<ag, 256, 65024, stream>>>(q_bf, key_bf, ni, Wb, bb, cs+4096,  nullptr, v_fin, v_part, out, alpha, beta);
}

// Round 4
// 943.906 us; speedup vs baseline: 1.4998x; 1.1037x over previous
//
#include <hip/hip_runtime.h>

#define N_NODES 50000
#define MPAD    50176   // 196*256 = 98*512
#define DIM     1024
#define HEAD    16
#define KV      128
#define HD      64
#define NGRP    98      // MPAD/512

typedef unsigned short ushort_t;
typedef short short8 __attribute__((ext_vector_type(8)));
typedef float f32x4 __attribute__((ext_vector_type(4)));

__device__ inline unsigned short f2bf(float f){
  union { float f; unsigned u; } v; v.f = f;
  unsigned u = v.u;
  unsigned r = (u + 0x7FFFu + ((u >> 16) & 1u)) >> 16;
  return (unsigned short)r;
}
__device__ inline float bf2f(unsigned short u){
  union { unsigned u; float f; } v; v.u = ((unsigned)u) << 16; return v.f;
}

__device__ inline void gload_lds16(const void* g, void* l){
  __builtin_amdgcn_global_load_lds(
      (const __attribute__((address_space(1))) void*)g,
      (__attribute__((address_space(3))) void*)l, 16, 0, 0);
}

// fragment loads: row-major [*][64] or [*][128] bf16 LDS tile, 16B-chunk XOR-swizzled by (row&7)
__device__ inline short8 frag64(const ushort_t* lds, int row, int kk, int lane){
  int c  = kk*4 + (lane >> 4);
  int cc = c ^ (row & 7);
  return *(const short8*)(lds + row*64 + cc*8);
}
__device__ inline short8 frag128(const ushort_t* lds, int row, int kk, int lane){
  int c  = kk*4 + (lane >> 4);
  int cc = c ^ (row & 7);
  return *(const short8*)(lds + row*128 + cc*8);
}

// ---------------- prep kernels ----------------
__global__ void k_zero(float* p, int n){
  int i = blockIdx.x*256 + threadIdx.x;
  if (i < n) p[i] = 0.f;
}

// x fp32 -> bf16, 16B-chunk swizzle keyed by row&7 (for global_load_lds staging)
__global__ void k_prep_x(const float* __restrict__ x, ushort_t* __restrict__ x_bf){
  int idx = blockIdx.x*256 + threadIdx.x;   // N_NODES*128 chunks of 8
  int row = idx >> 7, c = idx & 127;
  const float4* s = (const float4*)(x + (size_t)row*1024 + c*8);
  float4 f0 = s[0], f1 = s[1];
  short8 v;
  v[0]=(short)f2bf(f0.x); v[1]=(short)f2bf(f0.y); v[2]=(short)f2bf(f0.z); v[3]=(short)f2bf(f0.w);
  v[4]=(short)f2bf(f1.x); v[5]=(short)f2bf(f1.y); v[6]=(short)f2bf(f1.z); v[7]=(short)f2bf(f1.w);
  int sc = (c & ~7) | ((c ^ row) & 7);
  *(short8*)(x_bf + (size_t)row*1024 + sc*8) = v;
}

// W concat (rows 0..1023 = Wq, 1024..2047 = Wv), bf16, 16B-chunk swizzle keyed by row&7
__global__ void k_prep_w(const float* __restrict__ Wq, const float* __restrict__ Wv,
                         ushort_t* __restrict__ w_bf){
  int idx = blockIdx.x*256 + threadIdx.x;   // 2048*1024
  int j = idx >> 10, k = idx & 1023;
  float v = (j < 1024) ? Wq[idx] : Wv[(size_t)(j-1024)*1024 + k];
  int d = k & 63;
  int scol = (k & ~63) | ((((d>>3) ^ (j & 7)) & 7) << 3) | (d & 7);
  w_bf[(size_t)j*1024 + scol] = f2bf(v);
}

// key_bf[h][r][swz(d, r)]  from key_p[r][h][d]
__global__ void k_prep_key(const float* __restrict__ key_p, ushort_t* __restrict__ key_bf){
  int idx = blockIdx.x*256 + threadIdx.x;   // 16*128*64
  int h = idx >> 13, rem = idx & 8191;
  int r = rem >> 6, d = rem & 63;
  float v = key_p[(size_t)(r*HEAD + h)*HD + d];
  int pos = ((((d>>3) ^ (r & 7)) & 7) << 3) | (d & 7);
  key_bf[(size_t)h*8192 + r*64 + pos] = f2bf(v);
}

// sum the NGRP v-slices
__global__ void k_vreduce(const float* __restrict__ vp, float* __restrict__ vout){
  int i = blockIdx.x*256 + threadIdx.x;   // 131072
  float s = 0.f;
  for (int gg = 0; gg < NGRP; ++gg) s += vp[(size_t)gg*131072 + i];
  vout[i] = s;
}

// ---------------- big GEMM: [q|xv] = x @ [Wq;Wv]^T + [bq;bv] ----------------
// 256x256 tile, BK=64, 8 waves (2Mx4N), distance-2 prefetch w/ counted vmcnt.
// LDS 128KB dynamic: A[2][256][64] bf16, B[2][256][64] bf16.
__global__ __launch_bounds__(512) void k_gemm(const ushort_t* __restrict__ x_bf,
    const ushort_t* __restrict__ w_bf, const float* __restrict__ bq,
    const float* __restrict__ bv, ushort_t* __restrict__ q_bf, float* xv_out){
  extern __shared__ char gsm[];
  ushort_t* As = (ushort_t*)gsm;            // 2 x 32KB
  ushort_t* Bs = (ushort_t*)(gsm + 65536);  // 2 x 32KB
  const int tid = threadIdx.x, lane = tid & 63;
  const int wid = tid >> 6, wr = wid >> 2, wc = wid & 3;
  int b = blockIdx.x;
  int wg = (b & 7)*196 + (b >> 3);          // bijective XCD swizzle (1568 = 8*196)
  const int bm0 = (wg >> 3) * 256, bn0 = (wg & 7) * 256;

  f32x4 acc[8][4];
  #pragma unroll
  for (int m=0;m<8;m++)
    #pragma unroll
    for (int n=0;n<4;n++) acc[m][n] = (f32x4){0.f,0.f,0.f,0.f};

  const ushort_t* asrc = x_bf + (size_t)bm0*1024;
  const ushort_t* bsrc = w_bf + (size_t)bn0*1024;

#define STAGE(kt, bi)                                                    \
  { _Pragma("unroll")                                                    \
    for (int it=0; it<4; ++it){                                          \
      int chunk = it*512 + tid;                                          \
      int r = chunk >> 3, c = chunk & 7;                                 \
      gload_lds16(asrc + (size_t)r*1024 + (kt)*64 + c*8,                 \
                  As + (bi)*16384 + chunk*8);                            \
    }                                                                    \
    _Pragma("unroll")                                                    \
    for (int it=0; it<4; ++it){                                          \
      int chunk = it*512 + tid;                                          \
      int r = chunk >> 3, c = chunk & 7;                                 \
      gload_lds16(bsrc + (size_t)r*1024 + (kt)*64 + c*8,                 \
                  Bs + (bi)*16384 + chunk*8);                            \
    }                                                                    \
  }

  STAGE(0, 0);
  STAGE(1, 1);

  for (int kt = 0; kt < 16; ++kt){
    const int cur = kt & 1;
    if (kt == 15) { asm volatile("s_waitcnt vmcnt(0)" ::: "memory"); }
    else          { asm volatile("s_waitcnt vmcnt(8)" ::: "memory"); }
    __builtin_amdgcn_s_barrier();

    const ushort_t* ab  = As + cur*16384;
    const ushort_t* bb_ = Bs + cur*16384;
    #pragma unroll
    for (int kk=0;kk<2;kk++){
      short8 bfr[4];
      #pragma unroll
      for (int n=0;n<4;n++) bfr[n] = frag64(bb_, wc*64 + n*16 + (lane&15), kk, lane);
      #pragma unroll
      for (int m=0;m<8;m++){
        short8 af = frag64(ab, wr*128 + m*16 + (lane&15), kk, lane);
        #pragma unroll
        for (int n=0;n<4;n++)
          acc[m][n] = __builtin_amdgcn_mfma_f32_16x16x32_bf16(af, bfr[n], acc[m][n], 0,0,0);
      }
    }
    __builtin_amdgcn_s_barrier();
    if (kt + 2 < 16) STAGE(kt+2, cur);
  }
#undef STAGE

  // epilogue: bias, store (block is entirely q-half or entirely xv-half)
  const bool isq = bn0 < 1024;
  #pragma unroll
  for (int n=0;n<4;n++){
    int col = bn0 + wc*64 + n*16 + (lane & 15);
    float bias = isq ? bq[col] : bv[col - 1024];
    #pragma unroll
    for (int m=0;m<8;m++){
      #pragma unroll
      for (int j=0;j<4;j++){
        int row = bm0 + wr*128 + m*16 + (lane>>4)*4 + j;
        float val = acc[m][n][j] + bias;
        if (isq){
          int d = col & 63;
          int scol = (col & ~63) | ((((d>>3) ^ (row & 7)) & 7) << 3) | (d & 7);
          q_bf[(size_t)row*1024 + scol] = f2bf(val);
        } else if (row < N_NODES){
          xv_out[(size_t)row*1024 + (col - 1024)] = val;
        }
      }
    }
  }
}

// ---------------- attn passes (looped: 8 node-tiles of 64 per block) ----------------
// PHASE 0: colsumA = sum_n Q0 ; v_part[g] = sigmoid(attn)^T @ xv (reg-accum, plain store)
// PHASE 1: w=1/(128*cs_in); u=1/(50000*sum_r Q0*w); cs_out += sum_n u*Q0
// PHASE 2: w3,u3 -> cons = 50000*u3*Q0*w3 ; out = sig(a)*xv + sig(b)*(cons@v)
template<int PHASE>
__global__ __launch_bounds__(256) void k_attn(
    const ushort_t* __restrict__ q_bf, const ushort_t* __restrict__ key_bf,
    const float* __restrict__ node_index, const float* __restrict__ Wb,
    const float* __restrict__ bb, const float* __restrict__ colsum_in,
    float* __restrict__ colsum_out, const float* __restrict__ v_fin,
    float* __restrict__ v_part, float* xv_out,
    const float* __restrict__ alpha, const float* __restrict__ beta)
{
  constexpr int QB    = (PHASE == 2) ? 1 : 2;
  constexpr int O_Q   = 0;                     // QB x 64x64 bf16 (8KB each)
  constexpr int O_KEY = O_Q + QB*8192;         // 128x64 bf16 (16KB)
  constexpr int O_NI  = O_KEY + 16384;         // QB x 256 f32
  constexpr int O_WB  = O_NI + QB*1024;        // 128x5 f32
  constexpr int O_RED = O_WB + 2560;           // 512 f32
  constexpr int O_COL = O_RED + 2048;          // 128 f32
  constexpr int O_W   = O_COL + 512;           // 128 f32
  constexpr int O_X1  = O_W + 512;             // P0: sigT 128x64 swz ; P2: vT 64x[128] swz
  constexpr int O_X2  = O_X1 + 16384;          // P0: xvT 64x64 swz ; P2: cons(bf16 64x128)/out(f32 64x68)

  extern __shared__ char smem[];
  ushort_t* q_lds   = (ushort_t*)(smem + O_Q);
  ushort_t* key_lds = (ushort_t*)(smem + O_KEY);
  float* ni_lds  = (float*)(smem + O_NI);
  float* wb_lds  = (float*)(smem + O_WB);
  float* red_lds = (float*)(smem + O_RED);
  float* col_acc = (float*)(smem + O_COL);
  float* w_lds   = (float*)(smem + O_W);
  ushort_t* sigT     = (ushort_t*)(smem + O_X1);
  ushort_t* xvT      = (ushort_t*)(smem + O_X2);
  ushort_t* vT       = (ushort_t*)(smem + O_X1);
  ushort_t* cons_lds = (ushort_t*)(smem + O_X2);
  float*    out_lds  = (float*)(smem + O_X2);

  const int tid = threadIdx.x, lane = tid & 63, wid = tid >> 6;
  const int h    = blockIdx.x & 15;
  const int g    = blockIdx.x >> 4;
  const int base = g * 512;
  int NT = (MPAD - base) >> 6; if (NT > 8) NT = 8;

  // ---- prologue staging ----
  #pragma unroll
  for (int it = 0; it < 4; ++it){
    int chunk = it*256 + tid;
    gload_lds16(key_bf + (size_t)h*8192 + chunk*8, key_lds + chunk*8);
  }
  #pragma unroll
  for (int it = 0; it < 2; ++it){
    int chunk = it*256 + tid;
    int r = chunk >> 3, c = chunk & 7;
    gload_lds16(q_bf + (size_t)(base + r)*1024 + h*64 + c*8, q_lds + chunk*8);
  }
  { int r = tid >> 2, c = tid & 3;
    ni_lds[tid] = (base + r < N_NODES) ? node_index[(size_t)(base + r)*4 + c] : 0.f; }
  if (tid < 128){
    #pragma unroll
    for (int c=0;c<4;c++) wb_lds[tid*5+c] = Wb[(size_t)(h*128 + tid)*4 + c];
    wb_lds[tid*5+4] = bb[h*128 + tid];
    if (PHASE >= 1) w_lds[tid] = 1.f / (128.f * colsum_in[h*128 + tid]);
    if (PHASE <= 1) col_acc[tid] = 0.f;
  }
  if constexpr (PHASE == 2){
    int r = tid >> 1, dh = (tid & 1)*32;
    #pragma unroll
    for (int i=0;i<32;i++){
      int d = dh + i;
      vT[d*128 + ((r>>3) ^ (d&7))*8 + (r&7)] = f2bf(v_fin[((size_t)r*16 + h)*64 + d]);
    }
  }
  float xvr[16], xvn[16];
  if constexpr (PHASE == 0){
    int d = tid & 63, q4 = tid >> 6;
    #pragma unroll
    for (int i=0;i<16;i++){
      int row = base + q4*16 + i;
      xvr[i] = (row < N_NODES) ? xv_out[(size_t)row*1024 + h*64 + d] : 0.f;
    }
  }
  f32x4 vac[2][4];
  if constexpr (PHASE == 0)
    for (int m=0;m<2;m++) for (int n=0;n<4;n++) vac[m][n] = (f32x4){0.f,0.f,0.f,0.f};

  __syncthreads();

  // ---- main loop over node tiles ----
  for (int t = 0; t < NT; ++t){
    const int i0  = base + t*64;
    const int cur = t & 1;
    const ushort_t* qb  = q_lds  + ((QB==2) ? cur*4096 : 0);
    const float*    nib = ni_lds + ((QB==2) ? cur*256  : 0);
    float ni_next = 0.f;

    if constexpr (QB == 2){
      if (t+1 < NT){
        int i1 = i0 + 64;
        #pragma unroll
        for (int it = 0; it < 2; ++it){
          int chunk = it*256 + tid;
          int r = chunk >> 3, c = chunk & 7;
          gload_lds16(q_bf + (size_t)(i1 + r)*1024 + h*64 + c*8,
                      q_lds + (cur^1)*4096 + chunk*8);
        }
        int r = tid >> 2, c = tid & 3;
        ni_next = (i0 + 64 + r < N_NODES) ? node_index[(size_t)(i0+64+r)*4 + c] : 0.f;
      }
    } else {
      if (t+1 < NT){
        int r = tid >> 2, c = tid & 3;
        ni_next = (i0 + 64 + r < N_NODES) ? node_index[(size_t)(i0+64+r)*4 + c] : 0.f;
      }
    }
    if constexpr (PHASE == 0){
      if (t+1 < NT){
        int d = tid & 63, q4 = tid >> 6;
        #pragma unroll
        for (int i=0;i<16;i++){
          int row = i0 + 64 + q4*16 + i;
          xvn[i] = (row < N_NODES) ? xv_out[(size_t)row*1024 + h*64 + d] : 0.f;
        }
      }
    }

    // ---- attn^T = key @ q^T / 8 + bias^T ----
    f32x4 acc[2][4];
    for (int m=0;m<2;m++) for (int n=0;n<4;n++) acc[m][n] = (f32x4){0.f,0.f,0.f,0.f};
    #pragma unroll
    for (int kk = 0; kk < 2; ++kk){
      short8 kf[2];
      #pragma unroll
      for (int m=0;m<2;m++) kf[m] = frag64(key_lds, wid*32 + m*16 + (lane&15), kk, lane);
      #pragma unroll
      for (int n=0;n<4;n++){
        short8 qf = frag64(qb, n*16 + (lane&15), kk, lane);
        #pragma unroll
        for (int m=0;m<2;m++)
          acc[m][n] = __builtin_amdgcn_mfma_f32_16x16x32_bf16(kf[m], qf, acc[m][n], 0,0,0);
      }
    }

    float nif[4][4];
    #pragma unroll
    for (int n=0;n<4;n++){
      int nn = n*16 + (lane&15);
      #pragma unroll
      for (int c=0;c<4;c++) nif[n][c] = nib[nn*4+c];
    }
    float a[2][4][4];
    #pragma unroll
    for (int m=0;m<2;m++){
      #pragma unroll
      for (int j=0;j<4;j++){
        int r = wid*32 + m*16 + (lane>>4)*4 + j;
        float w0 = wb_lds[r*5+0], w1 = wb_lds[r*5+1];
        float w2 = wb_lds[r*5+2], w3 = wb_lds[r*5+3], w4 = wb_lds[r*5+4];
        #pragma unroll
        for (int n=0;n<4;n++){
          float b = w4 + w0*nif[n][0] + w1*nif[n][1] + w2*nif[n][2] + w3*nif[n][3];
          a[m][n][j] = acc[m][n][j]*0.125f + b;
        }
      }
    }

    float vmask[4];
    #pragma unroll
    for (int n=0;n<4;n++) vmask[n] = (i0 + n*16 + (lane&15) < N_NODES) ? 1.f : 0.f;

    if constexpr (PHASE == 0){
      // sigmoid -> sigT [r][nn] swizzled, masked
      #pragma unroll
      for (int m=0;m<2;m++) for (int n=0;n<4;n++) for (int j=0;j<4;j++){
        int r  = wid*32 + m*16 + (lane>>4)*4 + j;
        int nn = n*16 + (lane&15);
        float sg = vmask[n] / (1.f + __expf(-a[m][n][j]));
        sigT[r*64 + ((((nn>>3) ^ (r&7)) & 7) << 3) + (nn&7)] = f2bf(sg);
      }
      // xv^T -> xvT [d][nn] swizzled (from prefetched regs)
      { int d = tid & 63, q4 = tid >> 6;
        #pragma unroll
        for (int i=0;i<16;i++){
          int nn = q4*16 + i;
          xvT[d*64 + ((((nn>>3) ^ (d&7)) & 7) << 3) + (nn&7)] = f2bf(xvr[i]);
        }
      }
    }

    // ---- softmax over r ----
    float pm[4];
    #pragma unroll
    for (int n=0;n<4;n++){
      float m0 = a[0][n][0];
      #pragma unroll
      for (int m=0;m<2;m++) for (int j=0;j<4;j++) m0 = fmaxf(m0, a[m][n][j]);
      m0 = fmaxf(m0, __shfl_xor(m0, 16));
      m0 = fmaxf(m0, __shfl_xor(m0, 32));
      pm[n] = m0;
    }
    if (lane < 16){
      #pragma unroll
      for (int n=0;n<4;n++) red_lds[wid*64 + n*16 + lane] = pm[n];
    }
    __syncthreads();   // B: publishes red-max + sigT/xvT

    if constexpr (QB == 1){
      if (t+1 < NT){
        int i1 = i0 + 64;
        #pragma unroll
        for (int it = 0; it < 2; ++it){
          int chunk = it*256 + tid;
          int r = chunk >> 3, c = chunk & 7;
          gload_lds16(q_bf + (size_t)(i1 + r)*1024 + h*64 + c*8, q_lds + chunk*8);
        }
        ni_lds[tid] = ni_next;
      }
    }

    float mnn[4], snn[4];
    #pragma unroll
    for (int n=0;n<4;n++){
      int nn = n*16 + (lane&15);
      float m0 = red_lds[nn];
      m0 = fmaxf(m0, red_lds[64+nn]); m0 = fmaxf(m0, red_lds[128+nn]); m0 = fmaxf(m0, red_lds[192+nn]);
      mnn[n] = m0;
    }
    #pragma unroll
    for (int n=0;n<4;n++){
      float s = 0.f;
      #pragma unroll
      for (int m=0;m<2;m++) for (int j=0;j<4;j++){
        float e = __expf(a[m][n][j] - mnn[n]);
        a[m][n][j] = e; s += e;
      }
      s += __shfl_xor(s, 16); s += __shfl_xor(s, 32);
      snn[n] = s;
    }
    if (lane < 16){
      #pragma unroll
      for (int n=0;n<4;n++) red_lds[256 + wid*64 + n*16 + lane] = snn[n];
    }

    if constexpr (PHASE == 0){
      // vac += sigT @ xvT^T (accumulates across tiles)
      #pragma unroll
      for (int kk=0;kk<2;kk++){
        short8 sa[2];
        #pragma unroll
        for (int m=0;m<2;m++) sa[m] = frag64(sigT, wid*32 + m*16 + (lane&15), kk, lane);
        #pragma unroll
        for (int n=0;n<4;n++){
          short8 xf = frag64(xvT, n*16 + (lane&15), kk, lane);
          #pragma unroll
          for (int m=0;m<2;m++)
            vac[m][n] = __builtin_amdgcn_mfma_f32_16x16x32_bf16(sa[m], xf, vac[m][n], 0,0,0);
        }
      }
    }
    __syncthreads();   // C: publishes red-sum

    #pragma unroll
    for (int n=0;n<4;n++){
      int nn = n*16 + (lane&15);
      snn[n] = red_lds[256+nn] + red_lds[256+64+nn] + red_lds[256+128+nn] + red_lds[256+192+nn];
    }
    // Q0 = exp(20 * softmax)
    #pragma unroll
    for (int n=0;n<4;n++){
      float inv = 20.f / snn[n];
      #pragma unroll
      for (int m=0;m<2;m++) for (int j=0;j<4;j++)
        a[m][n][j] = __expf(a[m][n][j] * inv);
    }

    float uval[4];
    if constexpr (PHASE >= 1){
      #pragma unroll
      for (int n=0;n<4;n++){
        float s = 0.f;
        #pragma unroll
        for (int m=0;m<2;m++){
          #pragma unroll
          for (int j=0;j<4;j++){
            int r = wid*32 + m*16 + (lane>>4)*4 + j;
            s += a[m][n][j] * w_lds[r];
          }
        }
        s += __shfl_xor(s, 16); s += __shfl_xor(s, 32);
        uval[n] = s;
      }
      if (lane < 16){
        #pragma unroll
        for (int n=0;n<4;n++) red_lds[wid*64 + n*16 + lane] = uval[n];
      }
      __syncthreads();   // D
      #pragma unroll
      for (int n=0;n<4;n++){
        int nn = n*16 + (lane&15);
        float s = red_lds[nn] + red_lds[64+nn] + red_lds[128+nn] + red_lds[192+nn];
        uval[n] = 1.f / (50000.f * s);
      }
    }

    if constexpr (PHASE <= 1){
      float cs[2][4];
      #pragma unroll
      for (int m=0;m<2;m++){
        #pragma unroll
        for (int j=0;j<4;j++){
          float s = 0.f;
          #pragma unroll
          for (int n=0;n<4;n++){
            float tv = a[m][n][j] * vmask[n];
            if (PHASE == 1) tv *= uval[n];
            s += tv;
          }
          s += __shfl_xor(s, 1); s += __shfl_xor(s, 2);
          s += __shfl_xor(s, 4); s += __shfl_xor(s, 8);
          cs[m][j] = s;
        }
      }
      if ((lane & 15) == 0){
        #pragma unroll
        for (int m=0;m<2;m++) for (int j=0;j<4;j++){
          int r = wid*32 + m*16 + (lane>>4)*4 + j;
          col_acc[r] += cs[m][j];
        }
      }
    }

    if constexpr (PHASE == 2){
      #pragma unroll
      for (int m=0;m<2;m++) for (int n=0;n<4;n++) for (int j=0;j<4;j++){
        int r  = wid*32 + m*16 + (lane>>4)*4 + j;
        int nn = n*16 + (lane&15);
        float cv = 50000.f * uval[n] * a[m][n][j] * w_lds[r];
        cons_lds[nn*128 + ((r>>3) ^ (nn&7))*8 + (r&7)] = f2bf(cv);
      }
      __syncthreads();   // E: cons ready
      f32x4 oac[4];
      for (int n=0;n<4;n++) oac[n] = (f32x4){0.f,0.f,0.f,0.f};
      #pragma unroll
      for (int kk=0;kk<4;kk++){
        short8 va = frag128(vT, wid*16 + (lane&15), kk, lane);
        #pragma unroll
        for (int n=0;n<4;n++){
          short8 cf = frag128(cons_lds, n*16 + (lane&15), kk, lane);
          oac[n] = __builtin_amdgcn_mfma_f32_16x16x32_bf16(va, cf, oac[n], 0,0,0);
        }
      }
      __syncthreads();   // F: cons reads done -> reuse region as out_lds
      #pragma unroll
      for (int n=0;n<4;n++) for (int j=0;j<4;j++){
        int d  = wid*16 + (lane>>4)*4 + j;
        int nn = n*16 + (lane&15);
        out_lds[nn*68 + d] = oac[n][j];
      }
      __syncthreads();   // G (end-iter): publishes out_lds + q[t+1]
      float sa = 1.f/(1.f + __expf(-alpha[h]));
      float sb = 1.f/(1.f + __expf(-beta[h]));
      int nn = tid >> 2, d0 = (tid & 3)*16;
      if (i0 + nn < N_NODES){
        #pragma unroll
        for (int gq=0; gq<4; ++gq){
          float4 vf = *(const float4*)(out_lds + nn*68 + d0 + gq*4);
          float4 xf = *(const float4*)(xv_out + (size_t)(i0+nn)*1024 + h*64 + d0 + gq*4);
          float4 o;
          o.x = sa*xf.x + sb*vf.x;
          o.y = sa*xf.y + sb*vf.y;
          o.z = sa*xf.z + sb*vf.z;
          o.w = sa*xf.w + sb*vf.w;
          *(float4*)(xv_out + (size_t)(i0+nn)*1024 + h*64 + d0 + gq*4) = o;
        }
      }
    } else {
      if (t+1 < NT && QB == 2) ni_lds[(cur^1)*256 + tid] = ni_next;
      if constexpr (PHASE == 0){
        if (t+1 < NT){
          #pragma unroll
          for (int i=0;i<16;i++) xvr[i] = xvn[i];
        }
      }
      __syncthreads();   // end-iter: publishes q[t+1], ni[t+1]
    }
  }

  // ---- final flushes ----
  if constexpr (PHASE == 0){
    float* vdst = v_part + (size_t)g*131072;
    #pragma unroll
    for (int m=0;m<2;m++) for (int n=0;n<4;n++) for (int j=0;j<4;j++){
      int r = wid*32 + m*16 + (lane>>4)*4 + j;
      int d = n*16 + (lane&15);
      vdst[((size_t)r*16 + h)*64 + d] = vac[m][n][j];
    }
  }
  if constexpr (PHASE <= 1){
    if (tid < 128) atomicAdd(&colsum_out[h*128 + tid], col_acc[tid]);
  }
}

extern "C" void kernel_launch(void* const* d_in, const int* in_sizes, int n_in,
                              void* d_out, int out_size, void* d_ws, size_t ws_size,
                              hipStream_t stream){
  const float* x     = (const float*)d_in[0];
  const float* ni    = (const float*)d_in[1];
  const float* Wq    = (const float*)d_in[2];
  const float* bq    = (const float*)d_in[3];
  const float* keyp  = (const float*)d_in[4];
  const float* Wv    = (const float*)d_in[5];
  const float* bv    = (const float*)d_in[6];
  const float* alpha = (const float*)d_in[7];
  const float* beta  = (const float*)d_in[8];
  const float* Wb    = (const float*)d_in[9];
  const float* bb    = (const float*)d_in[10];
  float* out = (float*)d_out;

  char* ws = (char*)d_ws;
  ushort_t* x_bf   = (ushort_t*)(ws);                     // MPAD*1024 bf16 (dead after gemm)
  float*    v_part = (float*)(ws);                        // NGRP*131072 f32, overlays x_bf
  ushort_t* q_bf   = (ushort_t*)(ws + 102760448);         // MPAD*1024 bf16
  ushort_t* w_bf   = (ushort_t*)(ws + 205520896);         // 2048*1024 bf16
  ushort_t* key_bf = (ushort_t*)(ws + 209715200);         // 16*128*64 bf16
  float*    v_fin  = (float*)(ws + 209977344);            // 131072 f32
  float*    cs     = (float*)(ws + 210501632);            // 3*2048 f32

  (void)hipFuncSetAttribute((const void*)k_gemm,
      hipFuncAttributeMaxDynamicSharedMemorySize, 131072);

  k_zero<<<dim3(24), 256, 0, stream>>>(cs, 6144);
  // zero x_bf padding rows [50000, 50176): 176*1024 bf16 = 90112 f32
  k_zero<<<dim3(352), 256, 0, stream>>>((float*)(x_bf + (size_t)N_NODES*1024), 90112);
  k_prep_x<<<dim3(25000), 256, 0, stream>>>(x, x_bf);
  k_prep_w<<<dim3(2048*1024/256), 256, 0, stream>>>(Wq, Wv, w_bf);
  k_prep_key<<<dim3(HEAD*KV*HD/256), 256, 0, stream>>>(keyp, key_bf);
  k_gemm<<<dim3(1568), 512, 131072, stream>>>(x_bf, w_bf, bq, bv, q_bf, out);

  dim3 ag(NGRP*16);
  k_attn<0><<<ag, 256, 65024, stream>>>(q_bf, key_bf, ni, Wb, bb, nullptr,  cs,      v_fin, v_part, out, alpha, beta);
  k_vreduce<<<dim3(512), 256, 0, stream>>>(v_part, v_fin);
  k_attn<1><<<ag, 256, 40448, stream>>>(q_bf, key_bf, ni, Wb, bb, cs,       cs+2048, v_fin, v_part, out, alpha, beta);
  k_attn<1><<<ag, 256, 40448, stream>>>(q_bf, key_bf, ni, Wb, bb, cs+2048,  cs+4096, v_fin, v_part, out, alpha, beta);
  k_attn<2><<<ag, 256, 65024, stream>>>(q_bf, key_bf, ni, Wb, bb, cs+4096,  nullptr, v_fin, v_part, out, alpha, beta);
}